// Round 6
// baseline (904.333 us; speedup 1.0000x reference)
//
#include <hip/hip_runtime.h>

// ---------------------------------------------------------------------------
// ReadPath fused pipeline for MI355X (gfx950).
// B=4,T=2048 (BT=8192 rows), H=2048, heads=8, D=256, C=2048, N=4096, TOPK=64.
// Outputs (f32, concat): output[8192*2048], utility[8192*2048],
//                        attn[8192*8*64], retrieved[8192*2048].
// R5 baseline: 894.5 us. This round: attn occupancy (LDS 144->80KB, 1 head/wave,
// Q direct global->reg), topk float4 gather, cast_hidden 512 blocks.
// ---------------------------------------------------------------------------

typedef unsigned short ushort_t;
typedef unsigned int   uint_t;

typedef __bf16 bf16x8 __attribute__((ext_vector_type(8)));
typedef float  f32x4  __attribute__((ext_vector_type(4)));
typedef unsigned short u16x8 __attribute__((ext_vector_type(8)));
typedef unsigned short u16x4 __attribute__((ext_vector_type(4)));

#define DI static __device__ __forceinline__

DI ushort_t f2bf(float f) {
    union { float f; uint_t u; } v; v.f = f;
    uint_t u = v.u;
    uint_t r = (u + 0x7FFFu + ((u >> 16) & 1u)) >> 16;   // RNE
    return (ushort_t)r;
}
DI float bf2f(ushort_t b) {
    union { uint_t u; float f; } v; v.u = ((uint_t)b) << 16;
    return v.f;
}

#define GLL16(gp, lp) __builtin_amdgcn_global_load_lds( \
    (const __attribute__((address_space(1))) void*)(gp), \
    (__attribute__((address_space(3))) void*)(lp), 16, 0, 0)

// ---------------- problem constants ----------------
constexpr int BT  = 8192;     // B*T
constexpr int Hd  = 2048;     // hidden dim
constexpr int Dd  = 256;      // belief dim
constexpr int Cd  = 2048;     // h*D

// ---------------- workspace offsets (bytes) ----------------
constexpr size_t O_HID     = 0;                        // hidden bf16 / flat bf16  33,554,432
constexpr size_t O_WQ      = 33554432;                 // Wq bf16        8,388,608
constexpr size_t O_WOWU    = 41943040;                 // [Wo;Wu] bf16  16,777,216
constexpr size_t O_WG1     = 58720256;                 // Wg1 bf16       2,097,152
constexpr size_t O_QRY     = 60817408;                 // queries bf16 (reused as flat2) 33,554,432
constexpr size_t O_MEANACC = 94371840;                 // f32[2048]
constexpr size_t O_MEANQ   = 94380032;                 // f32[2048]
constexpr size_t O_RAD     = 94389248;                 // f32[4096]
constexpr size_t O_RSC     = 94405632;                 // f32[4096]
constexpr size_t O_KEYS    = 94422016;                 // bf16[64][256]
constexpr size_t O_VALT    = 94454784;                 // bf16[256][64]
constexpr size_t O_GB      = 94487552;                 // f32[8][64]
constexpr size_t O_HS      = 94489600;                 // f32[8] (padded)
constexpr size_t O_GP      = 94489856;                 // f32[8192] gate partial; end 94,522,624

// ---------------------------------------------------------------------------
// fused f32 -> bf16 cast of the four weight matrices (one launch)
// ---------------------------------------------------------------------------
__global__ void cast4_kernel(const float* __restrict__ sA, ushort_t* __restrict__ dA, int nA,
                             const float* __restrict__ sB, ushort_t* __restrict__ dB, int nB,
                             const float* __restrict__ sC, ushort_t* __restrict__ dC, int nC,
                             const float* __restrict__ sD, ushort_t* __restrict__ dD, int nD) {
    int total = (nA + nB + nC + nD) >> 2;
    for (int i = blockIdx.x * blockDim.x + threadIdx.x; i < total;
         i += gridDim.x * blockDim.x) {
        int e = i * 4;
        const float* s; ushort_t* d;
        if (e < nA)              { s = sA + e; d = dA + e; }
        else if ((e -= nA) < nB) { s = sB + e; d = dB + e; }
        else if ((e -= nB) < nC) { s = sC + e; d = dC + e; }
        else                     { e -= nC; s = sD + e; d = dD + e; }
        float4 v = *(const float4*)s;
        u16x4 o;
        o[0] = f2bf(v.x); o[1] = f2bf(v.y); o[2] = f2bf(v.z); o[3] = f2bf(v.w);
        *(u16x4*)d = o;
    }
}

// ---------------------------------------------------------------------------
// hidden: cast to bf16 + column-sum accumulation (for mean). 512 blocks x 256.
// Block handles 16 rows; thread covers 8 columns.
// ---------------------------------------------------------------------------
__global__ void cast_hidden_kernel(const float* __restrict__ hid, ushort_t* __restrict__ hbf,
                                   float* __restrict__ macc) {
    int r0 = blockIdx.x * 16;
    float s[8];
#pragma unroll
    for (int j = 0; j < 8; ++j) s[j] = 0.f;
    for (int r = 0; r < 16; ++r) {
        const float* rp = hid + (size_t)(r0 + r) * Hd;
        ushort_t*    wp = hbf + (size_t)(r0 + r) * Hd;
#pragma unroll
        for (int j = 0; j < 2; ++j) {
            int c = j * 1024 + threadIdx.x * 4;
            float4 v = *(const float4*)(rp + c);
            s[j*4+0] += v.x; s[j*4+1] += v.y; s[j*4+2] += v.z; s[j*4+3] += v.w;
            u16x4 o;
            o[0] = f2bf(v.x); o[1] = f2bf(v.y); o[2] = f2bf(v.z); o[3] = f2bf(v.w);
            *(u16x4*)(wp + c) = o;
        }
    }
#pragma unroll
    for (int j = 0; j < 2; ++j)
#pragma unroll
        for (int q = 0; q < 4; ++q)
            atomicAdd(macc + j * 1024 + threadIdx.x * 4 + q, s[j*4+q]);
}

// ---------------------------------------------------------------------------
// mean_q[c] = dot(mean_h, Wq[c,:])  (f32 exact path). One wave per output c.
// ---------------------------------------------------------------------------
__global__ void meanq_kernel(const float* __restrict__ macc, const float* __restrict__ Wq,
                             float* __restrict__ mq) {
    int wid = blockIdx.x * 4 + (threadIdx.x >> 6);
    int lane = threadIdx.x & 63;
    const float inv = 1.f / 8192.f;
    float s = 0.f;
    for (int k = lane; k < Hd; k += 64) s += macc[k] * inv * Wq[(size_t)wid * Hd + k];
#pragma unroll
    for (int m = 32; m; m >>= 1) s += __shfl_xor(s, m, 64);
    if (lane == 0) mq[wid] = s;
}

// ---------------------------------------------------------------------------
// per-belief radius + rough score (f32 exact). One wave per row.
// ---------------------------------------------------------------------------
__global__ void beliefs_kernel(const float* __restrict__ ab, const float* __restrict__ mq,
                               float* __restrict__ radii, float* __restrict__ rsc) {
    int n = blockIdx.x * 4 + (threadIdx.x >> 6);
    int lane = threadIdx.x & 63;
    float rqv[4];
#pragma unroll
    for (int j = 0; j < 4; ++j) {
        int d = lane + 64 * j;
        float s = 0.f;
#pragma unroll
        for (int hh = 0; hh < 8; ++hh) s += mq[hh * 256 + d];
        rqv[j] = s * 0.125f;
    }
    float v[4]; float r2 = 0.f;
#pragma unroll
    for (int j = 0; j < 4; ++j) { v[j] = ab[(size_t)n * Dd + lane + 64 * j]; r2 += v[j] * v[j]; }
#pragma unroll
    for (int m = 32; m; m >>= 1) r2 += __shfl_xor(r2, m, 64);
    float r = fmaxf(sqrtf(r2), 1e-8f);
    float dq = 0.f;
#pragma unroll
    for (int j = 0; j < 4; ++j) dq += (v[j] / r) * rqv[j];
#pragma unroll
    for (int m = 32; m; m >>= 1) dq += __shfl_xor(dq, m, 64);
    if (lane == 0) { radii[n] = r; rsc[n] = dq; }
}

// ---------------------------------------------------------------------------
// single-block: top-64 (desc, ties -> lower index), gather keys/values,
// goal angles, goal bias, head scales. float4 gather + f32x4 LDS scans.
// ---------------------------------------------------------------------------
__global__ void topk_kernel(const float* __restrict__ ab, const float* __restrict__ radii,
                            const float* __restrict__ rsc, const float* __restrict__ gemb,
                            const float* __restrict__ gprio, const float* __restrict__ Wgoal,
                            const float* __restrict__ ltemp,
                            ushort_t* __restrict__ keysg, ushort_t* __restrict__ valtg,
                            float* __restrict__ gbias, float* __restrict__ hscale) {
    __shared__ float s_sc[4096];
    __shared__ float s_rv[4];
    __shared__ int   s_ri[4];
    __shared__ int   s_top[64];
    __shared__ float s_ga[16 * 256];
    __shared__ float s_mga[256];
    __shared__ float s_gw[8];
    __shared__ float s_keyf[64 * 256];
    __shared__ float s_red[256];

    int t = threadIdx.x;
    int lane = t & 63, w = t >> 6;
    for (int it = 0; it < 16; ++it) s_sc[t + it * 256] = rsc[t + it * 256];
    __syncthreads();

    for (int kk = 0; kk < 64; ++kk) {
        float bv = -3.4e38f; int bi = 0x7fffffff;
#pragma unroll
        for (int j4 = 0; j4 < 4; ++j4) {
            f32x4 v4 = *(const f32x4*)&s_sc[t * 16 + j4 * 4];
#pragma unroll
            for (int q = 0; q < 4; ++q) {
                int idx = t * 16 + j4 * 4 + q;
                float v = v4[q];
                if (v > bv || (v == bv && idx < bi)) { bv = v; bi = idx; }
            }
        }
#pragma unroll
        for (int m = 32; m; m >>= 1) {
            float ov = __shfl_xor(bv, m, 64);
            int   oi = __shfl_xor(bi, m, 64);
            if (ov > bv || (ov == bv && oi < bi)) { bv = ov; bi = oi; }
        }
        if (lane == 0) { s_rv[w] = bv; s_ri[w] = bi; }
        __syncthreads();
        if (t == 0) {
            float fv = s_rv[0]; int fi = s_ri[0];
#pragma unroll
            for (int wv = 1; wv < 4; ++wv)
                if (s_rv[wv] > fv || (s_rv[wv] == fv && s_ri[wv] < fi)) { fv = s_rv[wv]; fi = s_ri[wv]; }
            s_top[kk] = fi; s_sc[fi] = -3.4e38f;
        }
        __syncthreads();
    }

    // gather keys (angles) + values(T): float4 loads, 4 threads per key row
    {
        int kk = t >> 2, dp = t & 3;
        int idx = s_top[kk];
        float r = radii[idx];
        const float4* src = (const float4*)(ab + (size_t)idx * Dd + dp * 64);
#pragma unroll 4
        for (int dd = 0; dd < 16; ++dd) {
            float4 v = src[dd];
            int d = dp * 64 + dd * 4;
            float k0 = v.x / r, k1 = v.y / r, k2 = v.z / r, k3 = v.w / r;
            s_keyf[kk * 256 + d + 0] = k0;
            s_keyf[kk * 256 + d + 1] = k1;
            s_keyf[kk * 256 + d + 2] = k2;
            s_keyf[kk * 256 + d + 3] = k3;
            u16x4 o;
            o[0] = f2bf(k0); o[1] = f2bf(k1); o[2] = f2bf(k2); o[3] = f2bf(k3);
            *(u16x4*)(keysg + kk * 256 + d) = o;
            valtg[(d + 0) * 64 + kk] = f2bf(v.x);
            valtg[(d + 1) * 64 + kk] = f2bf(v.y);
            valtg[(d + 2) * 64 + kk] = f2bf(v.z);
            valtg[(d + 3) * 64 + kk] = f2bf(v.w);
        }
    }
    // goal angles
    {
        for (int g = w; g < 16; g += 4) {
            float v[4]; float r2 = 0.f;
#pragma unroll
            for (int j = 0; j < 4; ++j) { v[j] = gemb[g * 256 + lane + 64 * j]; r2 += v[j] * v[j]; }
#pragma unroll
            for (int m = 32; m; m >>= 1) r2 += __shfl_xor(r2, m, 64);
            float r = fmaxf(sqrtf(r2), 1e-8f);
#pragma unroll
            for (int j = 0; j < 4; ++j) s_ga[g * 256 + lane + 64 * j] = v[j] / r;
        }
    }
    __syncthreads();
    {
        float s = 0.f;
        for (int g = 0; g < 16; ++g) s += s_ga[g * 256 + t];
        s_mga[t] = s * (1.f / 16.f);
    }
    __syncthreads();
    if (t < 8) {
        float s = 0.f;
        for (int d = 0; d < 256; ++d) s += Wgoal[t * 256 + d] * s_mga[d];
        s_gw[t] = 1.f / (1.f + expf(-s));
        hscale[t] = fmaxf(expf(ltemp[t] + 0.1f), 0.1f) * (1.f / 16.f);
    }
    __syncthreads();
    {
        int kk = t & 63, gq = t >> 6;
        const f32x4* kp = (const f32x4*)&s_keyf[kk * 256];
        float best = -3.4e38f;
        for (int g = gq * 4; g < gq * 4 + 4; ++g) {
            const f32x4* gp_ = (const f32x4*)&s_ga[g * 256];
            float dot = 0.f;
            for (int d4 = 0; d4 < 64; ++d4) {
                f32x4 a = kp[d4], b = gp_[d4];
                dot += a[0] * b[0] + a[1] * b[1] + a[2] * b[2] + a[3] * b[3];
            }
            best = fmaxf(best, dot * gprio[g]);
        }
        s_red[t] = best;
    }
    __syncthreads();
    if (t < 64) {
        float m = fmaxf(fmaxf(s_red[t], s_red[t + 64]), fmaxf(s_red[t + 128], s_red[t + 192]));
        for (int hh = 0; hh < 8; ++hh) gbias[hh * 64 + t] = s_gw[hh] * m;
    }
}

// ---------------------------------------------------------------------------
// bf16 GEMM  C = A[M,K] @ B[N,K]^T, 128x128 tile, BK=32, 4 waves, 16x16x32 MFMA.
// XCD-aware bijective block swizzle (nwg % 8 == 0 in all our launches).
// EPI 2: [output|utility] epilogue; gate computed inline from gpart+bg2.
// EPI 3: fused queries(N=2048, bf16 store) + gate-GEMM(cols 2048..2559,
//        ReLU*Wg2 row-reduce -> atomicAdd gpart). B-pointer selected per block.
// ---------------------------------------------------------------------------
template <int EPI>
__global__ __launch_bounds__(256)
void gemm_bt_kernel(const ushort_t* __restrict__ A, const ushort_t* __restrict__ Bw,
                    const ushort_t* __restrict__ Bw2, int Kd,
                    ushort_t* __restrict__ obf, float* __restrict__ of1, float* __restrict__ of2,
                    const float* __restrict__ bg1, const float* __restrict__ Wg2,
                    float* __restrict__ gpart, const float* __restrict__ bg2) {
    __shared__ ushort_t lA[128 * 32];
    __shared__ ushort_t lB[128 * 32];
    const int tid = threadIdx.x;
    const int lane = tid & 63;
    const int w = tid >> 6;
    const int wr = (w >> 1) * 64, wc = (w & 1) * 64;

    const int nwg = gridDim.x * gridDim.y;
    const int lin = blockIdx.y * gridDim.x + blockIdx.x;
    const int swz = (lin & 7) * (nwg >> 3) + (lin >> 3);
    const int bm = (swz / gridDim.x) * 128, bn = (swz % gridDim.x) * 128;

    f32x4 acc[4][4];
#pragma unroll
    for (int mi = 0; mi < 4; ++mi)
#pragma unroll
        for (int ni = 0; ni < 4; ++ni)
#pragma unroll
            for (int q = 0; q < 4; ++q) acc[mi][ni][q] = 0.f;

    const ushort_t* Ab = A + (size_t)bm * Kd;
    const ushort_t* Bb;
    if (EPI == 3 && bn >= 2048) Bb = Bw2 + (size_t)(bn - 2048) * Kd;
    else                        Bb = Bw + (size_t)bn * Kd;
    const int c0 = tid, c1 = tid + 256;

    for (int kt = 0; kt < Kd; kt += 32) {
        __syncthreads();
        GLL16(Ab + (size_t)(c0 >> 2) * Kd + kt + (c0 & 3) * 8, lA + c0 * 8);
        GLL16(Ab + (size_t)(c1 >> 2) * Kd + kt + (c1 & 3) * 8, lA + c1 * 8);
        GLL16(Bb + (size_t)(c0 >> 2) * Kd + kt + (c0 & 3) * 8, lB + c0 * 8);
        GLL16(Bb + (size_t)(c1 >> 2) * Kd + kt + (c1 & 3) * 8, lB + c1 * 8);
        __syncthreads();
        const int ko = (lane >> 4) * 8;
        bf16x8 af[4], bf[4];
#pragma unroll
        for (int mi = 0; mi < 4; ++mi)
            af[mi] = *(const bf16x8*)&lA[(wr + mi * 16 + (lane & 15)) * 32 + ko];
#pragma unroll
        for (int ni = 0; ni < 4; ++ni)
            bf[ni] = *(const bf16x8*)&lB[(wc + ni * 16 + (lane & 15)) * 32 + ko];
#pragma unroll
        for (int mi = 0; mi < 4; ++mi)
#pragma unroll
            for (int ni = 0; ni < 4; ++ni)
                acc[mi][ni] = __builtin_amdgcn_mfma_f32_16x16x32_bf16(af[mi], bf[ni], acc[mi][ni], 0, 0, 0);
    }

    if (EPI == 2) {
        const float b2 = bg2[0];
#pragma unroll
        for (int mi = 0; mi < 4; ++mi)
#pragma unroll
            for (int r = 0; r < 4; ++r) {
                int row = bm + wr + mi * 16 + (lane >> 4) * 4 + r;
                float g = gpart[row] + b2;
                float sg = (g > 0.f) ? 1.f : ((g < 0.f) ? -1.f : 0.f);
                float ss = sg * sqrtf(fmaxf(fabsf(g), 1e-6f));
                float gv = 1.f / (1.f + expf(-ss));
#pragma unroll
                for (int ni = 0; ni < 4; ++ni) {
                    int col = bn + wc + ni * 16 + (lane & 15);
                    float v = acc[mi][ni][r];
                    if (col < 2048) of1[(size_t)row * 2048 + col] = gv * v;
                    else            of2[(size_t)row * 2048 + (col - 2048)] = v;
                }
            }
    } else {  // EPI == 3
        if (bn < 2048) {
#pragma unroll
            for (int mi = 0; mi < 4; ++mi)
#pragma unroll
                for (int ni = 0; ni < 4; ++ni)
#pragma unroll
                    for (int r = 0; r < 4; ++r) {
                        int row = bm + wr + mi * 16 + (lane >> 4) * 4 + r;
                        int col = bn + wc + ni * 16 + (lane & 15);
                        obf[(size_t)row * 2048 + col] = f2bf(acc[mi][ni][r]);
                    }
        } else {
            float wg[4], bb[4];
#pragma unroll
            for (int ni = 0; ni < 4; ++ni) {
                int col = bn + wc + ni * 16 + (lane & 15) - 2048;
                wg[ni] = Wg2[col]; bb[ni] = bg1[col];
            }
#pragma unroll
            for (int mi = 0; mi < 4; ++mi)
#pragma unroll
                for (int r = 0; r < 4; ++r) {
                    float s = 0.f;
#pragma unroll
                    for (int ni = 0; ni < 4; ++ni) {
                        float v = acc[mi][ni][r] + bb[ni];
                        v = fmaxf(v, 0.f);
                        s += v * wg[ni];
                    }
#pragma unroll
                    for (int m = 8; m; m >>= 1) s += __shfl_xor(s, m, 64);
                    if ((lane & 15) == 0)
                        atomicAdd(gpart + bm + wr + mi * 16 + (lane >> 4) * 4 + r, s);
                }
        }
    }
}

// ---------------------------------------------------------------------------
// attention: 32 rows/block, 4 waves, 1 head/wave; grid (256 rowgroups, 2 headgroups).
// Q loaded直接 global->reg (16B fragments, L3-hot). LDS 80KB -> 2 blocks/CU.
// Writes attn (f32 out), retrieved (f32 out), flat (bf16 ws).
// ---------------------------------------------------------------------------
__global__ __launch_bounds__(256, 2)
void attn_kernel(const ushort_t* __restrict__ qry, const ushort_t* __restrict__ keysg,
                 const ushort_t* __restrict__ valtg, const float* __restrict__ gbias,
                 const float* __restrict__ hscale, float* __restrict__ attn_out,
                 float* __restrict__ retr_out, ushort_t* __restrict__ flatb) {
    __shared__ ushort_t sK[64 * 256];    // [key][k], 512B rows, swizzled   32KB
    __shared__ ushort_t sV[256 * 64];    // [d][key], 128B rows, swizzled   32KB
    __shared__ ushort_t sP[4][32 * 64];  // per wave, 128B rows, swizzled   16KB

    const int tid = threadIdx.x, lane = tid & 63, w = tid >> 6;
    const int r0 = blockIdx.x * 32;
    const int head = blockIdx.y * 4 + w;

    for (int it = 0; it < 8; ++it) {
        int f = it * 256 + tid;
        int row = f >> 5, cb = f & 31;
        u16x8 v = *(const u16x8*)(keysg + f * 8);
        int byte = (row * 512 + cb * 16) ^ ((row & 7) << 4);
        *(u16x8*)((char*)sK + byte) = v;
    }
    for (int it = 0; it < 8; ++it) {
        int f = it * 256 + tid;
        int row = f >> 3, cb = f & 7;
        u16x8 v = *(const u16x8*)(valtg + f * 8);
        int byte = (row * 128 + cb * 16) ^ ((row & 7) << 4);
        *(u16x8*)((char*)sV + byte) = v;
    }
    __syncthreads();

    char* sPw = (char*)sP[w];
    const float hs = hscale[head];
    float gb[4];
#pragma unroll
    for (int ni = 0; ni < 4; ++ni) gb[ni] = gbias[head * 64 + ni * 16 + (lane & 15)];

    // Q fragment base: row = r0 + mi*16 + (lane&15), k = kt*32 + (lane>>4)*8
    const ushort_t* qbase = qry + (size_t)r0 * Cd + head * 256
                          + (size_t)(lane & 15) * Cd + (lane >> 4) * 8;

    // scores: M=32 (mi 0..1), N=64 (ni 0..3), K=256 (kt 0..7)
    f32x4 accs[2][4];
#pragma unroll
    for (int mi = 0; mi < 2; ++mi)
#pragma unroll
        for (int ni = 0; ni < 4; ++ni)
#pragma unroll
            for (int q = 0; q < 4; ++q) accs[mi][ni][q] = 0.f;

#pragma unroll
    for (int kt = 0; kt < 8; ++kt) {
        const int kb = kt * 64 + (lane >> 4) * 16;
        bf16x8 aq[2], bk[4];
#pragma unroll
        for (int mi = 0; mi < 2; ++mi)
            aq[mi] = *(const bf16x8*)(qbase + (size_t)(mi * 16) * Cd + kt * 32);
#pragma unroll
        for (int ni = 0; ni < 4; ++ni) {
            int n = ni * 16 + (lane & 15);
            bk[ni] = *(const bf16x8*)((const char*)sK + ((n * 512 + kb) ^ ((n & 7) << 4)));
        }
#pragma unroll
        for (int mi = 0; mi < 2; ++mi)
#pragma unroll
            for (int ni = 0; ni < 4; ++ni)
                accs[mi][ni] = __builtin_amdgcn_mfma_f32_16x16x32_bf16(aq[mi], bk[ni], accs[mi][ni], 0, 0, 0);
    }

    // softmax over 64 keys per row; write attn f32 + sP bf16
#pragma unroll
    for (int mi = 0; mi < 2; ++mi)
#pragma unroll
        for (int r = 0; r < 4; ++r) {
            float sc[4];
            float mx = -3.4e38f;
#pragma unroll
            for (int ni = 0; ni < 4; ++ni) {
                sc[ni] = accs[mi][ni][r] * hs + gb[ni];
                mx = fmaxf(mx, sc[ni]);
            }
#pragma unroll
            for (int m = 8; m; m >>= 1) mx = fmaxf(mx, __shfl_xor(mx, m, 64));
            float p[4]; float sm = 0.f;
#pragma unroll
            for (int ni = 0; ni < 4; ++ni) { p[ni] = expf(sc[ni] - mx); sm += p[ni]; }
#pragma unroll
            for (int m = 8; m; m >>= 1) sm += __shfl_xor(sm, m, 64);
            float inv = 1.f / sm;
            int row = mi * 16 + (lane >> 4) * 4 + r;
            size_t ob = (size_t)(r0 + row) * 512 + head * 64;
#pragma unroll
            for (int ni = 0; ni < 4; ++ni) {
                float a = p[ni] * inv;
                int col = ni * 16 + (lane & 15);
                attn_out[ob + col] = a;
                int byte = (row * 128 + col * 2) ^ ((row & 7) << 4);
                *(ushort_t*)(sPw + byte) = f2bf(a);
            }
        }

    // PV: M=32 (mi 0..1), N=256 (ni 0..15), K=64 (kt 0..1)
    f32x4 accr[2][16];
#pragma unroll
    for (int mi = 0; mi < 2; ++mi)
#pragma unroll
        for (int ni = 0; ni < 16; ++ni)
#pragma unroll
            for (int q = 0; q < 4; ++q) accr[mi][ni][q] = 0.f;

#pragma unroll
    for (int kt = 0; kt < 2; ++kt) {
        const int kb = kt * 64 + (lane >> 4) * 16;
        bf16x8 ap[2];
#pragma unroll
        for (int mi = 0; mi < 2; ++mi) {
            int m = mi * 16 + (lane & 15);
            ap[mi] = *(const bf16x8*)(sPw + ((m * 128 + kb) ^ ((m & 7) << 4)));
        }
#pragma unroll
        for (int ni = 0; ni < 16; ++ni) {
            int n = ni * 16 + (lane & 15);
            bf16x8 bv = *(const bf16x8*)((const char*)sV + ((n * 128 + kb) ^ ((n & 7) << 4)));
            accr[0][ni] = __builtin_amdgcn_mfma_f32_16x16x32_bf16(ap[0], bv, accr[0][ni], 0, 0, 0);
            accr[1][ni] = __builtin_amdgcn_mfma_f32_16x16x32_bf16(ap[1], bv, accr[1][ni], 0, 0, 0);
        }
    }

#pragma unroll
    for (int mi = 0; mi < 2; ++mi)
#pragma unroll
        for (int ni = 0; ni < 16; ++ni)
#pragma unroll
            for (int r = 0; r < 4; ++r) {
                int row = mi * 16 + (lane >> 4) * 4 + r;
                int d = ni * 16 + (lane & 15);
                float v = accr[mi][ni][r];
                size_t o = (size_t)(r0 + row) * Cd + head * 256 + d;
                retr_out[o] = v;
                flatb[o] = f2bf(v);
            }
}

// ---------------------------------------------------------------------------
// depthwise causal conv (k=4, left pad 3) + SiLU residual, 4 channels/thread.
// flat2 = flat + silu(conv). Grid (2, 64, 4) x 256: t-chunks of 32.
// ---------------------------------------------------------------------------
__global__ void conv_kernel(const ushort_t* __restrict__ flat, const float* __restrict__ cw,
                            ushort_t* __restrict__ flat2) {
    int cq = blockIdx.x * 256 + threadIdx.x;      // 0..511
    int c  = cq * 4;
    int b  = blockIdx.z;
    int t0 = blockIdx.y * 32;
    float4 wv[4];
#pragma unroll
    for (int j = 0; j < 4; ++j) wv[j] = *(const float4*)(cw + (size_t)(c + j) * 4);
    size_t base = (size_t)b * 2048 * Cd + c;
    float xm3[4], xm2[4], xm1[4];
    if (t0 == 0) {
#pragma unroll
        for (int j = 0; j < 4; ++j) { xm3[j] = 0.f; xm2[j] = 0.f; xm1[j] = 0.f; }
    } else {
        u16x4 a3 = *(const u16x4*)(flat + base + (size_t)(t0 - 3) * Cd);
        u16x4 a2 = *(const u16x4*)(flat + base + (size_t)(t0 - 2) * Cd);
        u16x4 a1 = *(const u16x4*)(flat + base + (size_t)(t0 - 1) * Cd);
#pragma unroll
        for (int j = 0; j < 4; ++j) { xm3[j] = bf2f(a3[j]); xm2[j] = bf2f(a2[j]); xm1[j] = bf2f(a1[j]); }
    }
    for (int t = t0; t < t0 + 32; ++t) {
        u16x4 xv = *(const u16x4*)(flat + base + (size_t)t * Cd);
        u16x4 ov;
#pragma unroll
        for (int j = 0; j < 4; ++j) {
            float x = bf2f(xv[j]);
            float cv = wv[j].x * xm3[j] + wv[j].y * xm2[j] + wv[j].z * xm1[j] + wv[j].w * x;
            float sl = cv / (1.f + expf(-cv));
            ov[j] = f2bf(x + sl);
            xm3[j] = xm2[j]; xm2[j] = xm1[j]; xm1[j] = x;
        }
        *(u16x4*)(flat2 + base + (size_t)t * Cd) = ov;
    }
}

// ---------------------------------------------------------------------------
extern "C" void kernel_launch(void* const* d_in, const int* in_sizes, int n_in,
                              void* d_out, int out_size, void* d_ws, size_t ws_size,
                              hipStream_t stream) {
    (void)in_sizes; (void)n_in; (void)out_size; (void)ws_size;
    const float* hid   = (const float*)d_in[0];
    const float* ab    = (const float*)d_in[1];
    const float* gemb  = (const float*)d_in[2];
    const float* gprio = (const float*)d_in[3];
    const float* Wq    = (const float*)d_in[4];
    const float* Wo    = (const float*)d_in[5];
    const float* Wgoal = (const float*)d_in[6];
    const float* ltemp = (const float*)d_in[7];
    const float* Wu    = (const float*)d_in[8];
    const float* Wg1   = (const float*)d_in[9];
    const float* bg1   = (const float*)d_in[10];
    const float* Wg2   = (const float*)d_in[11];
    const float* bg2   = (const float*)d_in[12];
    const float* cw    = (const float*)d_in[13];

    float* out      = (float*)d_out;
    float* out_util = out + 16777216;
    float* out_attn = out + 33554432;
    float* out_retr = out + 37748736;

    char* ws = (char*)d_ws;
    ushort_t* hbf    = (ushort_t*)(ws + O_HID);   // hidden bf16, later reused as flat
    ushort_t* wqb    = (ushort_t*)(ws + O_WQ);
    ushort_t* wowub  = (ushort_t*)(ws + O_WOWU);
    ushort_t* wg1b   = (ushort_t*)(ws + O_WG1);
    ushort_t* qryb   = (ushort_t*)(ws + O_QRY);   // queries, later reused as flat2
    ushort_t* flatb  = hbf;                       // alias: attn runs after GEMM on hidden
    float* macc   = (float*)(ws + O_MEANACC);
    float* meanq  = (float*)(ws + O_MEANQ);
    float* radii  = (float*)(ws + O_RAD);
    float* rsc    = (float*)(ws + O_RSC);
    ushort_t* keysb = (ushort_t*)(ws + O_KEYS);
    ushort_t* valtb = (ushort_t*)(ws + O_VALT);
    float* gbias  = (float*)(ws + O_GB);
    float* hscale = (float*)(ws + O_HS);
    float* gpart  = (float*)(ws + O_GP);

    hipMemsetAsync(ws + O_MEANACC, 0, 2048 * 4, stream);
    hipMemsetAsync(ws + O_GP, 0, 8192 * 4, stream);

    cast_hidden_kernel<<<512, 256, 0, stream>>>(hid, hbf, macc);
    cast4_kernel<<<2048, 256, 0, stream>>>(Wq, wqb, 2048 * 2048,
                                           Wo, wowub, 2048 * 2048,
                                           Wu, wowub + 2048 * 2048, 2048 * 2048,
                                           Wg1, wg1b, 512 * 2048);

    meanq_kernel<<<512, 256, 0, stream>>>(macc, Wq, meanq);
    beliefs_kernel<<<1024, 256, 0, stream>>>(ab, meanq, radii, rsc);
    topk_kernel<<<1, 256, 0, stream>>>(ab, radii, rsc, gemb, gprio, Wgoal, ltemp,
                                       keysb, valtb, gbias, hscale);

    // fused: queries = hidden @ Wq^T (cols 0..2047 -> bf16) and
    //        gate partials (cols 2048..2559: relu(hidden@Wg1^T+bg1)*Wg2 -> gpart)
    gemm_bt_kernel<3><<<dim3(20, 64), 256, 0, stream>>>(hbf, wqb, wg1b, 2048,
        qryb, nullptr, nullptr, bg1, Wg2, gpart, nullptr);

    // attn overwrites the hidden-bf16 region with flat (safe: GEMM above done)
    attn_kernel<<<dim3(256, 2), 256, 0, stream>>>(qryb, keysb, valtb, gbias, hscale,
                                                  out_attn, out_retr, flatb);

    conv_kernel<<<dim3(2, 64, 4), 256, 0, stream>>>(flatb, cw, qryb /* flat2 */);

    // [output | utility] = flat2 @ [Wo;Wu]^T; gate from gpart+bg2 inline
    gemm_bt_kernel<2><<<dim3(32, 64), 256, 0, stream>>>(qryb, wowub, nullptr, 2048,
        nullptr, out, out_util, nullptr, nullptr, gpart, bg2);
}

// Round 8
// 877.257 us; speedup vs baseline: 1.0309x; 1.0309x over previous
//
#include <hip/hip_runtime.h>

// ---------------------------------------------------------------------------
// ReadPath fused pipeline for MI355X (gfx950).
// B=4,T=2048 (BT=8192 rows), H=2048, heads=8, D=256, C=2048, N=4096, TOPK=64.
// R5 baseline 894.5us; R6 904.3us (EPI2 gemm 233us, MfmaUtil 25%).
// R7/R8: 256^2-tile 8-wave counted-vmcnt GEMM (triple-buffer BK=32, raw
//        barrier, both-sides LDS XOR swizzle), single merged memset.
//        (R7 never ran - GPU timeout; resubmitted after re-audit.)
// ---------------------------------------------------------------------------

typedef unsigned short ushort_t;
typedef unsigned int   uint_t;

typedef __bf16 bf16x8 __attribute__((ext_vector_type(8)));
typedef float  f32x4  __attribute__((ext_vector_type(4)));
typedef unsigned short u16x8 __attribute__((ext_vector_type(8)));
typedef unsigned short u16x4 __attribute__((ext_vector_type(4)));

#define DI static __device__ __forceinline__

DI ushort_t f2bf(float f) {
    union { float f; uint_t u; } v; v.f = f;
    uint_t u = v.u;
    uint_t r = (u + 0x7FFFu + ((u >> 16) & 1u)) >> 16;   // RNE
    return (ushort_t)r;
}
DI float bf2f(ushort_t b) {
    union { uint_t u; float f; } v; v.u = ((uint_t)b) << 16;
    return v.f;
}

#define GLL16(gp, lp) __builtin_amdgcn_global_load_lds( \
    (const __attribute__((address_space(1))) void*)(gp), \
    (__attribute__((address_space(3))) void*)(lp), 16, 0, 0)

// ---------------- problem constants ----------------
constexpr int BT  = 8192;     // B*T
constexpr int Hd  = 2048;     // hidden dim
constexpr int Dd  = 256;      // belief dim
constexpr int Cd  = 2048;     // h*D

// ---------------- workspace offsets (bytes) ----------------
constexpr size_t O_HID     = 0;                        // hidden bf16 / flat bf16  33,554,432
constexpr size_t O_WQ      = 33554432;                 // Wq bf16        8,388,608
constexpr size_t O_WOWU    = 41943040;                 // [Wo;Wu] bf16  16,777,216
constexpr size_t O_WG1     = 58720256;                 // Wg1 bf16       2,097,152
constexpr size_t O_QRY     = 60817408;                 // queries bf16 (reused as flat2) 33,554,432
constexpr size_t O_MEANACC = 94371840;                 // f32[2048]
constexpr size_t O_MEANQ   = 94380032;                 // f32[2048]
constexpr size_t O_RAD     = 94389248;                 // f32[4096]
constexpr size_t O_RSC     = 94405632;                 // f32[4096]
constexpr size_t O_KEYS    = 94422016;                 // bf16[64][256]
constexpr size_t O_VALT    = 94454784;                 // bf16[256][64]
constexpr size_t O_GB      = 94487552;                 // f32[8][64]
constexpr size_t O_HS      = 94489600;                 // f32[8] (padded)
constexpr size_t O_GP      = 94489856;                 // f32[8192] gate partial; end 94,522,624
constexpr size_t MEMSET_SZ = 94522624 - O_MEANACC;     // one memset covers all small bufs

// ---------------------------------------------------------------------------
// fused f32 -> bf16 cast of the four weight matrices (one launch)
// ---------------------------------------------------------------------------
__global__ void cast4_kernel(const float* __restrict__ sA, ushort_t* __restrict__ dA, int nA,
                             const float* __restrict__ sB, ushort_t* __restrict__ dB, int nB,
                             const float* __restrict__ sC, ushort_t* __restrict__ dC, int nC,
                             const float* __restrict__ sD, ushort_t* __restrict__ dD, int nD) {
    int total = (nA + nB + nC + nD) >> 2;
    for (int i = blockIdx.x * blockDim.x + threadIdx.x; i < total;
         i += gridDim.x * blockDim.x) {
        int e = i * 4;
        const float* s; ushort_t* d;
        if (e < nA)              { s = sA + e; d = dA + e; }
        else if ((e -= nA) < nB) { s = sB + e; d = dB + e; }
        else if ((e -= nB) < nC) { s = sC + e; d = dC + e; }
        else                     { e -= nC; s = sD + e; d = dD + e; }
        float4 v = *(const float4*)s;
        u16x4 o;
        o[0] = f2bf(v.x); o[1] = f2bf(v.y); o[2] = f2bf(v.z); o[3] = f2bf(v.w);
        *(u16x4*)d = o;
    }
}

// ---------------------------------------------------------------------------
// hidden: cast to bf16 + column-sum accumulation (for mean). 512 blocks x 256.
// ---------------------------------------------------------------------------
__global__ void cast_hidden_kernel(const float* __restrict__ hid, ushort_t* __restrict__ hbf,
                                   float* __restrict__ macc) {
    int r0 = blockIdx.x * 16;
    float s[8];
#pragma unroll
    for (int j = 0; j < 8; ++j) s[j] = 0.f;
    for (int r = 0; r < 16; ++r) {
        const float* rp = hid + (size_t)(r0 + r) * Hd;
        ushort_t*    wp = hbf + (size_t)(r0 + r) * Hd;
#pragma unroll
        for (int j = 0; j < 2; ++j) {
            int c = j * 1024 + threadIdx.x * 4;
            float4 v = *(const float4*)(rp + c);
            s[j*4+0] += v.x; s[j*4+1] += v.y; s[j*4+2] += v.z; s[j*4+3] += v.w;
            u16x4 o;
            o[0] = f2bf(v.x); o[1] = f2bf(v.y); o[2] = f2bf(v.z); o[3] = f2bf(v.w);
            *(u16x4*)(wp + c) = o;
        }
    }
#pragma unroll
    for (int j = 0; j < 2; ++j)
#pragma unroll
        for (int q = 0; q < 4; ++q)
            atomicAdd(macc + j * 1024 + threadIdx.x * 4 + q, s[j*4+q]);
}

// ---------------------------------------------------------------------------
// mean_q[c] = dot(mean_h, Wq[c,:])  (f32 exact path). One wave per output c.
// ---------------------------------------------------------------------------
__global__ void meanq_kernel(const float* __restrict__ macc, const float* __restrict__ Wq,
                             float* __restrict__ mq) {
    int wid = blockIdx.x * 4 + (threadIdx.x >> 6);
    int lane = threadIdx.x & 63;
    const float inv = 1.f / 8192.f;
    float s = 0.f;
    for (int k = lane; k < Hd; k += 64) s += macc[k] * inv * Wq[(size_t)wid * Hd + k];
#pragma unroll
    for (int m = 32; m; m >>= 1) s += __shfl_xor(s, m, 64);
    if (lane == 0) mq[wid] = s;
}

// ---------------------------------------------------------------------------
// per-belief radius + rough score (f32 exact). One wave per row.
// ---------------------------------------------------------------------------
__global__ void beliefs_kernel(const float* __restrict__ ab, const float* __restrict__ mq,
                               float* __restrict__ radii, float* __restrict__ rsc) {
    int n = blockIdx.x * 4 + (threadIdx.x >> 6);
    int lane = threadIdx.x & 63;
    float rqv[4];
#pragma unroll
    for (int j = 0; j < 4; ++j) {
        int d = lane + 64 * j;
        float s = 0.f;
#pragma unroll
        for (int hh = 0; hh < 8; ++hh) s += mq[hh * 256 + d];
        rqv[j] = s * 0.125f;
    }
    float v[4]; float r2 = 0.f;
#pragma unroll
    for (int j = 0; j < 4; ++j) { v[j] = ab[(size_t)n * Dd + lane + 64 * j]; r2 += v[j] * v[j]; }
#pragma unroll
    for (int m = 32; m; m >>= 1) r2 += __shfl_xor(r2, m, 64);
    float r = fmaxf(sqrtf(r2), 1e-8f);
    float dq = 0.f;
#pragma unroll
    for (int j = 0; j < 4; ++j) dq += (v[j] / r) * rqv[j];
#pragma unroll
    for (int m = 32; m; m >>= 1) dq += __shfl_xor(dq, m, 64);
    if (lane == 0) { radii[n] = r; rsc[n] = dq; }
}

// ---------------------------------------------------------------------------
// single-block: top-64 (desc, ties -> lower index), gather keys/values,
// goal angles, goal bias, head scales.
// ---------------------------------------------------------------------------
__global__ void topk_kernel(const float* __restrict__ ab, const float* __restrict__ radii,
                            const float* __restrict__ rsc, const float* __restrict__ gemb,
                            const float* __restrict__ gprio, const float* __restrict__ Wgoal,
                            const float* __restrict__ ltemp,
                            ushort_t* __restrict__ keysg, ushort_t* __restrict__ valtg,
                            float* __restrict__ gbias, float* __restrict__ hscale) {
    __shared__ float s_sc[4096];
    __shared__ float s_rv[4];
    __shared__ int   s_ri[4];
    __shared__ int   s_top[64];
    __shared__ float s_ga[16 * 256];
    __shared__ float s_mga[256];
    __shared__ float s_gw[8];
    __shared__ float s_keyf[64 * 256];
    __shared__ float s_red[256];

    int t = threadIdx.x;
    int lane = t & 63, w = t >> 6;
    for (int it = 0; it < 16; ++it) s_sc[t + it * 256] = rsc[t + it * 256];
    __syncthreads();

    for (int kk = 0; kk < 64; ++kk) {
        float bv = -3.4e38f; int bi = 0x7fffffff;
#pragma unroll
        for (int j4 = 0; j4 < 4; ++j4) {
            f32x4 v4 = *(const f32x4*)&s_sc[t * 16 + j4 * 4];
#pragma unroll
            for (int q = 0; q < 4; ++q) {
                int idx = t * 16 + j4 * 4 + q;
                float v = v4[q];
                if (v > bv || (v == bv && idx < bi)) { bv = v; bi = idx; }
            }
        }
#pragma unroll
        for (int m = 32; m; m >>= 1) {
            float ov = __shfl_xor(bv, m, 64);
            int   oi = __shfl_xor(bi, m, 64);
            if (ov > bv || (ov == bv && oi < bi)) { bv = ov; bi = oi; }
        }
        if (lane == 0) { s_rv[w] = bv; s_ri[w] = bi; }
        __syncthreads();
        if (t == 0) {
            float fv = s_rv[0]; int fi = s_ri[0];
#pragma unroll
            for (int wv = 1; wv < 4; ++wv)
                if (s_rv[wv] > fv || (s_rv[wv] == fv && s_ri[wv] < fi)) { fv = s_rv[wv]; fi = s_ri[wv]; }
            s_top[kk] = fi; s_sc[fi] = -3.4e38f;
        }
        __syncthreads();
    }

    {
        int kk = t >> 2, dp = t & 3;
        int idx = s_top[kk];
        float r = radii[idx];
        const float4* src = (const float4*)(ab + (size_t)idx * Dd + dp * 64);
#pragma unroll 4
        for (int dd = 0; dd < 16; ++dd) {
            float4 v = src[dd];
            int d = dp * 64 + dd * 4;
            float k0 = v.x / r, k1 = v.y / r, k2 = v.z / r, k3 = v.w / r;
            s_keyf[kk * 256 + d + 0] = k0;
            s_keyf[kk * 256 + d + 1] = k1;
            s_keyf[kk * 256 + d + 2] = k2;
            s_keyf[kk * 256 + d + 3] = k3;
            u16x4 o;
            o[0] = f2bf(k0); o[1] = f2bf(k1); o[2] = f2bf(k2); o[3] = f2bf(k3);
            *(u16x4*)(keysg + kk * 256 + d) = o;
            valtg[(d + 0) * 64 + kk] = f2bf(v.x);
            valtg[(d + 1) * 64 + kk] = f2bf(v.y);
            valtg[(d + 2) * 64 + kk] = f2bf(v.z);
            valtg[(d + 3) * 64 + kk] = f2bf(v.w);
        }
    }
    {
        for (int g = w; g < 16; g += 4) {
            float v[4]; float r2 = 0.f;
#pragma unroll
            for (int j = 0; j < 4; ++j) { v[j] = gemb[g * 256 + lane + 64 * j]; r2 += v[j] * v[j]; }
#pragma unroll
            for (int m = 32; m; m >>= 1) r2 += __shfl_xor(r2, m, 64);
            float r = fmaxf(sqrtf(r2), 1e-8f);
#pragma unroll
            for (int j = 0; j < 4; ++j) s_ga[g * 256 + lane + 64 * j] = v[j] / r;
        }
    }
    __syncthreads();
    {
        float s = 0.f;
        for (int g = 0; g < 16; ++g) s += s_ga[g * 256 + t];
        s_mga[t] = s * (1.f / 16.f);
    }
    __syncthreads();
    if (t < 8) {
        float s = 0.f;
        for (int d = 0; d < 256; ++d) s += Wgoal[t * 256 + d] * s_mga[d];
        s_gw[t] = 1.f / (1.f + expf(-s));
        hscale[t] = fmaxf(expf(ltemp[t] + 0.1f), 0.1f) * (1.f / 16.f);
    }
    __syncthreads();
    {
        int kk = t & 63, gq = t >> 6;
        const f32x4* kp = (const f32x4*)&s_keyf[kk * 256];
        float best = -3.4e38f;
        for (int g = gq * 4; g < gq * 4 + 4; ++g) {
            const f32x4* gp_ = (const f32x4*)&s_ga[g * 256];
            float dot = 0.f;
            for (int d4 = 0; d4 < 64; ++d4) {
                f32x4 a = kp[d4], b = gp_[d4];
                dot += a[0] * b[0] + a[1] * b[1] + a[2] * b[2] + a[3] * b[3];
            }
            best = fmaxf(best, dot * gprio[g]);
        }
        s_red[t] = best;
    }
    __syncthreads();
    if (t < 64) {
        float m = fmaxf(fmaxf(s_red[t], s_red[t + 64]), fmaxf(s_red[t + 128], s_red[t + 192]));
        for (int hh = 0; hh < 8; ++hh) gbias[hh * 64 + t] = s_gw[hh] * m;
    }
}

// ---------------------------------------------------------------------------
// bf16 GEMM C = A[M,K] @ B[N,K]^T. 256x256 tile, BK=32, 8 waves (512 thr),
// triple-buffered LDS (96KB), counted vmcnt(4) pipeline, raw s_barrier
// (1 barrier/K-tile), both-sides XOR swizzle cb^=(row&3)^((row>>2)&3).
// Per-wave output 128x64 (8x4 16x16x32 frags).
// EPI 2: [output|utility], gate inline from gpart+bg2.
// EPI 3: queries (bn<2048, bf16) + gate-GEMM (bn>=2048 -> atomicAdd gpart).
// ---------------------------------------------------------------------------
template <int EPI>
__global__ __launch_bounds__(512, 2)
void gemm_bt_kernel(const ushort_t* __restrict__ A, const ushort_t* __restrict__ Bw,
                    const ushort_t* __restrict__ Bw2, int Kd,
                    ushort_t* __restrict__ obf, float* __restrict__ of1, float* __restrict__ of2,
                    const float* __restrict__ bg1, const float* __restrict__ Wg2,
                    float* __restrict__ gpart, const float* __restrict__ bg2) {
    // [slot 0..2][A:0|B:1][8192 ushort]  = 96 KB
    __shared__ __align__(16) ushort_t lds[3 * 16384];

    const int tid  = threadIdx.x;
    const int lane = tid & 63;
    const int w    = tid >> 6;
    const int wr   = (w >> 2) * 128;     // 2 wave-rows
    const int wc   = (w & 3) * 64;       // 4 wave-cols

    // XCD swizzle (nwg % 8 == 0)
    const int nwg = gridDim.x * gridDim.y;
    const int lin = blockIdx.y * gridDim.x + blockIdx.x;
    const int swz = (lin & 7) * (nwg >> 3) + (lin >> 3);
    const int bm = (swz / gridDim.x) * 256, bn = (swz % gridDim.x) * 256;

    const ushort_t* Ab = A + (size_t)bm * Kd;
    const ushort_t* Bb;
    if (EPI == 3 && bn >= 2048) Bb = Bw2 + (size_t)(bn - 2048) * Kd;
    else                        Bb = Bw + (size_t)bn * Kd;

    // staging map: chunk c -> row = c>>2, phys cb = c&3; fetch logical
    // cbl = cb ^ (row&3) ^ ((row>>2)&3) so that LDS holds the swizzled layout.
    const int c0 = tid, c1 = tid + 512;
    const int r0s = c0 >> 2, r1s = c1 >> 2;
    const int cbl0 = (c0 & 3) ^ (r0s & 3) ^ ((r0s >> 2) & 3);
    const int cbl1 = (c1 & 3) ^ (r1s & 3) ^ ((r1s >> 2) & 3);
    const size_t src0 = (size_t)r0s * Kd + cbl0 * 8;
    const size_t src1 = (size_t)r1s * Kd + cbl1 * 8;

    // reader: physical chunk per lane (mi/ni-independent)
    const int pcb = (lane >> 4) ^ (lane & 3) ^ ((lane >> 2) & 3);
    const int aBase = (wr + (lane & 15)) * 32 + pcb * 8;
    const int bBase = 8192 + (wc + (lane & 15)) * 32 + pcb * 8;

    f32x4 acc[8][4];
#pragma unroll
    for (int mi = 0; mi < 8; ++mi)
#pragma unroll
        for (int ni = 0; ni < 4; ++ni)
#pragma unroll
            for (int q = 0; q < 4; ++q) acc[mi][ni][q] = 0.f;

    const int NT = Kd >> 5;   // K-tiles of 32

#define STAGE_T(t_, slot_) do {                                            \
        const ushort_t* As_ = Ab + (size_t)(t_) * 32;                      \
        const ushort_t* Bs_ = Bb + (size_t)(t_) * 32;                      \
        ushort_t* ls_ = lds + (slot_) * 16384;                             \
        GLL16(As_ + src0, ls_ + c0 * 8);                                   \
        GLL16(As_ + src1, ls_ + c1 * 8);                                   \
        GLL16(Bs_ + src0, ls_ + 8192 + c0 * 8);                            \
        GLL16(Bs_ + src1, ls_ + 8192 + c1 * 8);                            \
    } while (0)

    // prologue: stage tiles 0 and 1
    STAGE_T(0, 0);
    STAGE_T(1, 1);

    int slot = 0;
    for (int t = 0; t < NT; ++t) {
        if (t >= NT - 2) asm volatile("s_waitcnt vmcnt(0)" ::: "memory");
        else             asm volatile("s_waitcnt vmcnt(4)" ::: "memory");
        __builtin_amdgcn_s_barrier();
        __builtin_amdgcn_sched_barrier(0);

        const ushort_t* sl = lds + slot * 16384;
        bf16x8 afr[8], bfr[4];
#pragma unroll
        for (int mi = 0; mi < 8; ++mi)
            afr[mi] = *(const bf16x8*)(sl + aBase + mi * 512);
#pragma unroll
        for (int ni = 0; ni < 4; ++ni)
            bfr[ni] = *(const bf16x8*)(sl + bBase + ni * 512);

        if (t + 2 < NT) {
            int s2 = slot + 2; if (s2 >= 3) s2 -= 3;
            STAGE_T(t + 2, s2);
        }

        __builtin_amdgcn_s_setprio(1);
#pragma unroll
        for (int mi = 0; mi < 8; ++mi)
#pragma unroll
            for (int ni = 0; ni < 4; ++ni)
                acc[mi][ni] = __builtin_amdgcn_mfma_f32_16x16x32_bf16(afr[mi], bfr[ni], acc[mi][ni], 0, 0, 0);
        __builtin_amdgcn_s_setprio(0);

        ++slot; if (slot >= 3) slot = 0;
    }
#undef STAGE_T

    if (EPI == 2) {
        const float b2 = bg2[0];
#pragma unroll
        for (int mi = 0; mi < 8; ++mi)
#pragma unroll
            for (int r = 0; r < 4; ++r) {
                int row = bm + wr + mi * 16 + (lane >> 4) * 4 + r;
                float g = gpart[row] + b2;
                float sg = (g > 0.f) ? 1.f : ((g < 0.f) ? -1.f : 0.f);
                float ss = sg * sqrtf(fmaxf(fabsf(g), 1e-6f));
                float gv = 1.f / (1.f + expf(-ss));
#pragma unroll
                for (int ni = 0; ni < 4; ++ni) {
                    int col = bn + wc + ni * 16 + (lane & 15);
                    float v = acc[mi][ni][r];
                    if (col < 2048) of1[(size_t)row * 2048 + col] = gv * v;
                    else            of2[(size_t)row * 2048 + (col - 2048)] = v;
                }
            }
    } else {  // EPI == 3
        if (bn < 2048) {
#pragma unroll
            for (int mi = 0; mi < 8; ++mi)
#pragma unroll
                for (int ni = 0; ni < 4; ++ni)
#pragma unroll
                    for (int r = 0; r < 4; ++r) {
                        int row = bm + wr + mi * 16 + (lane >> 4) * 4 + r;
                        int col = bn + wc + ni * 16 + (lane & 15);
                        obf[(size_t)row * 2048 + col] = f2bf(acc[mi][ni][r]);
                    }
        } else {
            float wg[4], bb[4];
#pragma unroll
            for (int ni = 0; ni < 4; ++ni) {
                int col = bn + wc + ni * 16 + (lane & 15) - 2048;
                wg[ni] = Wg2[col]; bb[ni] = bg1[col];
            }
#pragma unroll
            for (int mi = 0; mi < 8; ++mi)
#pragma unroll
                for (int r = 0; r < 4; ++r) {
                    float s = 0.f;
#pragma unroll
                    for (int ni = 0; ni < 4; ++ni) {
                        float v = acc[mi][ni][r] + bb[ni];
                        v = fmaxf(v, 0.f);
                        s += v * wg[ni];
                    }
#pragma unroll
                    for (int m = 8; m; m >>= 1) s += __shfl_xor(s, m, 64);
                    if ((lane & 15) == 0)
                        atomicAdd(gpart + bm + wr + mi * 16 + (lane >> 4) * 4 + r, s);
                }
        }
    }
}

// ---------------------------------------------------------------------------
// attention: 32 rows/block, 4 waves, 1 head/wave; grid (256, 2).
// Q direct global->reg; LDS 80KB -> 2 blocks/CU.
// ---------------------------------------------------------------------------
__global__ __launch_bounds__(256, 2)
void attn_kernel(const ushort_t* __restrict__ qry, const ushort_t* __restrict__ keysg,
                 const ushort_t* __restrict__ valtg, const float* __restrict__ gbias,
                 const float* __restrict__ hscale, float* __restrict__ attn_out,
                 float* __restrict__ retr_out, ushort_t* __restrict__ flatb) {
    __shared__ ushort_t sK[64 * 256];
    __shared__ ushort_t sV[256 * 64];
    __shared__ ushort_t sP[4][32 * 64];

    const int tid = threadIdx.x, lane = tid & 63, w = tid >> 6;
    const int r0 = blockIdx.x * 32;
    const int head = blockIdx.y * 4 + w;

    for (int it = 0; it < 8; ++it) {
        int f = it * 256 + tid;
        int row = f >> 5, cb = f & 31;
        u16x8 v = *(const u16x8*)(keysg + f * 8);
        int byte = (row * 512 + cb * 16) ^ ((row & 7) << 4);
        *(u16x8*)((char*)sK + byte) = v;
    }
    for (int it = 0; it < 8; ++it) {
        int f = it * 256 + tid;
        int row = f >> 3, cb = f & 7;
        u16x8 v = *(const u16x8*)(valtg + f * 8);
        int byte = (row * 128 + cb * 16) ^ ((row & 7) << 4);
        *(u16x8*)((char*)sV + byte) = v;
    }
    __syncthreads();

    char* sPw = (char*)sP[w];
    const float hs = hscale[head];
    float gb[4];
#pragma unroll
    for (int ni = 0; ni < 4; ++ni) gb[ni] = gbias[head * 64 + ni * 16 + (lane & 15)];

    const ushort_t* qbase = qry + (size_t)r0 * Cd + head * 256
                          + (size_t)(lane & 15) * Cd + (lane >> 4) * 8;

    f32x4 accs[2][4];
#pragma unroll
    for (int mi = 0; mi < 2; ++mi)
#pragma unroll
        for (int ni = 0; ni < 4; ++ni)
#pragma unroll
            for (int q = 0; q < 4; ++q) accs[mi][ni][q] = 0.f;

#pragma unroll
    for (int kt = 0; kt < 8; ++kt) {
        const int kb = kt * 64 + (lane >> 4) * 16;
        bf16x8 aq[2], bk[4];
#pragma unroll
        for (int mi = 0; mi < 2; ++mi)
            aq[mi] = *(const bf16x8*)(qbase + (size_t)(mi * 16) * Cd + kt * 32);
#pragma unroll
        for (int ni = 0; ni < 4; ++ni) {
            int n = ni * 16 + (lane & 15);
            bk[ni] = *(const bf16x8*)((const char*)sK + ((n * 512 + kb) ^ ((n & 7) << 4)));
        }
#pragma unroll
        for (int mi = 0; mi < 2; ++mi)
#pragma unroll
            for (int ni = 0; ni < 4; ++ni)
                accs[mi][ni] = __builtin_amdgcn_mfma_f32_16x16x32_bf16(aq[mi], bk[ni], accs[mi][ni], 0, 0, 0);
    }

#pragma unroll
    for (int mi = 0; mi < 2; ++mi)
#pragma unroll
        for (int r = 0; r < 4; ++r) {
            float sc[4];
            float mx = -3.4e38f;
#pragma unroll
            for (int ni = 0; ni < 4; ++ni) {
                sc[ni] = accs[mi][ni][r] * hs + gb[ni];
                mx = fmaxf(mx, sc[ni]);
            }
#pragma unroll
            for (int m = 8; m; m >>= 1) mx = fmaxf(mx, __shfl_xor(mx, m, 64));
            float p[4]; float sm = 0.f;
#pragma unroll
            for (int ni = 0; ni < 4; ++ni) { p[ni] = expf(sc[ni] - mx); sm += p[ni]; }
#pragma unroll
            for (int m = 8; m; m >>= 1) sm += __shfl_xor(sm, m, 64);
            float inv = 1.f / sm;
            int row = mi * 16 + (lane >> 4) * 4 + r;
            size_t ob = (size_t)(r0 + row) * 512 + head * 64;
#pragma unroll
            for (int ni = 0; ni < 4; ++ni) {
                float a = p[ni] * inv;
                int col = ni * 16 + (lane & 15);
                attn_out[ob + col] = a;
                int byte = (row * 128 + col * 2) ^ ((row & 7) << 4);
                *(ushort_t*)(sPw + byte) = f2bf(a);
            }
        }

    f32x4 accr[2][16];
#pragma unroll
    for (int mi = 0; mi < 2; ++mi)
#pragma unroll
        for (int ni = 0; ni < 16; ++ni)
#pragma unroll
            for (int q = 0; q < 4; ++q) accr[mi][ni][q] = 0.f;

#pragma unroll
    for (int kt = 0; kt < 2; ++kt) {
        const int kb = kt * 64 + (lane >> 4) * 16;
        bf16x8 ap[2];
#pragma unroll
        for (int mi = 0; mi < 2; ++mi) {
            int m = mi * 16 + (lane & 15);
            ap[mi] = *(const bf16x8*)(sPw + ((m * 128 + kb) ^ ((m & 7) << 4)));
        }
#pragma unroll
        for (int ni = 0; ni < 16; ++ni) {
            int n = ni * 16 + (lane & 15);
            bf16x8 bv = *(const bf16x8*)((const char*)sV + ((n * 128 + kb) ^ ((n & 7) << 4)));
            accr[0][ni] = __builtin_amdgcn_mfma_f32_16x16x32_bf16(ap[0], bv, accr[0][ni], 0, 0, 0);
            accr[1][ni] = __builtin_amdgcn_mfma_f32_16x16x32_bf16(ap[1], bv, accr[1][ni], 0, 0, 0);
        }
    }

#pragma unroll
    for (int mi = 0; mi < 2; ++mi)
#pragma unroll
        for (int ni = 0; ni < 16; ++ni)
#pragma unroll
            for (int r = 0; r < 4; ++r) {
                int row = mi * 16 + (lane >> 4) * 4 + r;
                int d = ni * 16 + (lane & 15);
                float v = accr[mi][ni][r];
                size_t o = (size_t)(r0 + row) * Cd + head * 256 + d;
                retr_out[o] = v;
                flatb[o] = f2bf(v);
            }
}

// ---------------------------------------------------------------------------
// depthwise causal conv (k=4) + SiLU residual, 4 channels/thread.
// ---------------------------------------------------------------------------
__global__ void conv_kernel(const ushort_t* __restrict__ flat, const float* __restrict__ cw,
                            ushort_t* __restrict__ flat2) {
    int cq = blockIdx.x * 256 + threadIdx.x;
    int c  = cq * 4;
    int b  = blockIdx.z;
    int t0 = blockIdx.y * 32;
    float4 wv[4];
#pragma unroll
    for (int j = 0; j < 4; ++j) wv[j] = *(const float4*)(cw + (size_t)(c + j) * 4);
    size_t base = (size_t)b * 2048 * Cd + c;
    float xm3[4], xm2[4], xm1[4];
    if (t0 == 0) {
#pragma unroll
        for (int j = 0; j < 4; ++j) { xm3[j] = 0.f; xm2[j] = 0.f; xm1[j] = 0.f; }
    } else {
        u16x4 a3 = *(const u16x4*)(flat + base + (size_t)(t0 - 3) * Cd);
        u16x4 a2 = *(const u16x4*)(flat + base + (size_t)(t0 - 2) * Cd);
        u16x4 a1 = *(const u16x4*)(flat + base + (size_t)(t0 - 1) * Cd);
#pragma unroll
        for (int j = 0; j < 4; ++j) { xm3[j] = bf2f(a3[j]); xm2[j] = bf2f(a2[j]); xm1[j] = bf2f(a1[j]); }
    }
    for (int t = t0; t < t0 + 32; ++t) {
        u16x4 xv = *(const u16x4*)(flat + base + (size_t)t * Cd);
        u16x4 ov;
#pragma unroll
        for (int j = 0; j < 4; ++j) {
            float x = bf2f(xv[j]);
            float cv = wv[j].x * xm3[j] + wv[j].y * xm2[j] + wv[j].z * xm1[j] + wv[j].w * x;
            float sl = cv / (1.f + expf(-cv));
            ov[j] = f2bf(x + sl);
            xm3[j] = xm2[j]; xm2[j] = xm1[j]; xm1[j] = x;
        }
        *(u16x4*)(flat2 + base + (size_t)t * Cd) = ov;
    }
}

// ---------------------------------------------------------------------------
extern "C" void kernel_launch(void* const* d_in, const int* in_sizes, int n_in,
                              void* d_out, int out_size, void* d_ws, size_t ws_size,
                              hipStream_t stream) {
    (void)in_sizes; (void)n_in; (void)out_size; (void)ws_size;
    const float* hid   = (const float*)d_in[0];
    const float* ab    = (const float*)d_in[1];
    const float* gemb  = (const float*)d_in[2];
    const float* gprio = (const float*)d_in[3];
    const float* Wq    = (const float*)d_in[4];
    const float* Wo    = (const float*)d_in[5];
    const float* Wgoal = (const float*)d_in[6];
    const float* ltemp = (const float*)d_in[7];
    const float* Wu    = (const float*)d_in[8];
    const float* Wg1   = (const float*)d_in[9];
    const float* bg1   = (const float*)d_in[10];
    const float* Wg2   = (const float*)d_in[11];
    const float* bg2   = (const float*)d_in[12];
    const float* cw    = (const float*)d_in[13];

    float* out      = (float*)d_out;
    float* out_util = out + 16777216;
    float* out_attn = out + 33554432;
    float* out_retr = out + 37748736;

    char* ws = (char*)d_ws;
    ushort_t* hbf    = (ushort_t*)(ws + O_HID);
    ushort_t* wqb    = (ushort_t*)(ws + O_WQ);
    ushort_t* wowub  = (ushort_t*)(ws + O_WOWU);
    ushort_t* wg1b   = (ushort_t*)(ws + O_WG1);
    ushort_t* qryb   = (ushort_t*)(ws + O_QRY);
    ushort_t* flatb  = hbf;                       // alias: attn after GEMM on hidden
    float* macc   = (float*)(ws + O_MEANACC);
    float* meanq  = (float*)(ws + O_MEANQ);
    float* radii  = (float*)(ws + O_RAD);
    float* rsc    = (float*)(ws + O_RSC);
    ushort_t* keysb = (ushort_t*)(ws + O_KEYS);
    ushort_t* valtb = (ushort_t*)(ws + O_VALT);
    float* gbias  = (float*)(ws + O_GB);
    float* hscale = (float*)(ws + O_HS);
    float* gpart  = (float*)(ws + O_GP);

    hipMemsetAsync(ws + O_MEANACC, 0, MEMSET_SZ, stream);

    cast_hidden_kernel<<<512, 256, 0, stream>>>(hid, hbf, macc);
    cast4_kernel<<<2048, 256, 0, stream>>>(Wq, wqb, 2048 * 2048,
                                           Wo, wowub, 2048 * 2048,
                                           Wu, wowub + 2048 * 2048, 2048 * 2048,
                                           Wg1, wg1b, 512 * 2048);

    meanq_kernel<<<512, 256, 0, stream>>>(macc, Wq, meanq);
    beliefs_kernel<<<1024, 256, 0, stream>>>(ab, meanq, radii, rsc);
    topk_kernel<<<1, 256, 0, stream>>>(ab, radii, rsc, gemb, gprio, Wgoal, ltemp,
                                       keysb, valtb, gbias, hscale);

    // fused queries + gate partials: 256-tiles, cols 0..2047 queries, 2048..2559 gate
    gemm_bt_kernel<3><<<dim3(10, 32), 512, 0, stream>>>(hbf, wqb, wg1b, 2048,
        qryb, nullptr, nullptr, bg1, Wg2, gpart, nullptr);

    attn_kernel<<<dim3(256, 2), 256, 0, stream>>>(qryb, keysb, valtb, gbias, hscale,
                                                  out_attn, out_retr, flatb);

    conv_kernel<<<dim3(2, 64, 4), 256, 0, stream>>>(flatb, cw, qryb /* flat2 */);

    // [output | utility] = flat2 @ [Wo;Wu]^T; gate from gpart+bg2 inline
    gemm_bt_kernel<2><<<dim3(16, 32), 512, 0, stream>>>(qryb, wowub, nullptr, 2048,
        nullptr, out, out_util, nullptr, nullptr, gpart, bg2);
}

// Round 9
// 826.163 us; speedup vs baseline: 1.0946x; 1.0618x over previous
//
#include <hip/hip_runtime.h>

// ---------------------------------------------------------------------------
// ReadPath fused pipeline for MI355X (gfx950).
// B=4,T=2048 (BT=8192 rows), H=2048, heads=8, D=256, C=2048, N=4096, TOPK=64.
// R6 904us (128^2 gemm: EPI2 233, MfmaUtil 25%); R8 877us (256^2 1blk/CU:
// EPI2 194, MfmaUtil 30%, Occ 23% -> latency-bound, EPI3 tail-quantized).
// R9: 256x128 tile, 4 waves, triple-buffer 72KB -> 2 blocks/CU; same counted
//     vmcnt skeleton (now vmcnt(6)); grids 32x32 / 20x32.
// ---------------------------------------------------------------------------

typedef unsigned short ushort_t;
typedef unsigned int   uint_t;

typedef __bf16 bf16x8 __attribute__((ext_vector_type(8)));
typedef float  f32x4  __attribute__((ext_vector_type(4)));
typedef unsigned short u16x8 __attribute__((ext_vector_type(8)));
typedef unsigned short u16x4 __attribute__((ext_vector_type(4)));

#define DI static __device__ __forceinline__

DI ushort_t f2bf(float f) {
    union { float f; uint_t u; } v; v.f = f;
    uint_t u = v.u;
    uint_t r = (u + 0x7FFFu + ((u >> 16) & 1u)) >> 16;   // RNE
    return (ushort_t)r;
}
DI float bf2f(ushort_t b) {
    union { uint_t u; float f; } v; v.u = ((uint_t)b) << 16;
    return v.f;
}

#define GLL16(gp, lp) __builtin_amdgcn_global_load_lds( \
    (const __attribute__((address_space(1))) void*)(gp), \
    (__attribute__((address_space(3))) void*)(lp), 16, 0, 0)

// ---------------- problem constants ----------------
constexpr int BT  = 8192;     // B*T
constexpr int Hd  = 2048;     // hidden dim
constexpr int Dd  = 256;      // belief dim
constexpr int Cd  = 2048;     // h*D

// ---------------- workspace offsets (bytes) ----------------
constexpr size_t O_HID     = 0;                        // hidden bf16 / flat bf16  33,554,432
constexpr size_t O_WQ      = 33554432;                 // Wq bf16        8,388,608
constexpr size_t O_WOWU    = 41943040;                 // [Wo;Wu] bf16  16,777,216
constexpr size_t O_WG1     = 58720256;                 // Wg1 bf16       2,097,152
constexpr size_t O_QRY     = 60817408;                 // queries bf16 (reused as flat2) 33,554,432
constexpr size_t O_MEANACC = 94371840;                 // f32[2048]
constexpr size_t O_MEANQ   = 94380032;                 // f32[2048]
constexpr size_t O_RAD     = 94389248;                 // f32[4096]
constexpr size_t O_RSC     = 94405632;                 // f32[4096]
constexpr size_t O_KEYS    = 94422016;                 // bf16[64][256]
constexpr size_t O_VALT    = 94454784;                 // bf16[256][64]
constexpr size_t O_GB      = 94487552;                 // f32[8][64]
constexpr size_t O_HS      = 94489600;                 // f32[8] (padded)
constexpr size_t O_GP      = 94489856;                 // f32[8192] gate partial; end 94,522,624
constexpr size_t MEMSET_SZ = 94522624 - O_MEANACC;     // one memset covers all small bufs

// ---------------------------------------------------------------------------
// fused f32 -> bf16 cast of the four weight matrices (one launch)
// ---------------------------------------------------------------------------
__global__ void cast4_kernel(const float* __restrict__ sA, ushort_t* __restrict__ dA, int nA,
                             const float* __restrict__ sB, ushort_t* __restrict__ dB, int nB,
                             const float* __restrict__ sC, ushort_t* __restrict__ dC, int nC,
                             const float* __restrict__ sD, ushort_t* __restrict__ dD, int nD) {
    int total = (nA + nB + nC + nD) >> 2;
    for (int i = blockIdx.x * blockDim.x + threadIdx.x; i < total;
         i += gridDim.x * blockDim.x) {
        int e = i * 4;
        const float* s; ushort_t* d;
        if (e < nA)              { s = sA + e; d = dA + e; }
        else if ((e -= nA) < nB) { s = sB + e; d = dB + e; }
        else if ((e -= nB) < nC) { s = sC + e; d = dC + e; }
        else                     { e -= nC; s = sD + e; d = dD + e; }
        float4 v = *(const float4*)s;
        u16x4 o;
        o[0] = f2bf(v.x); o[1] = f2bf(v.y); o[2] = f2bf(v.z); o[3] = f2bf(v.w);
        *(u16x4*)d = o;
    }
}

// ---------------------------------------------------------------------------
// hidden: cast to bf16 + column-sum accumulation (for mean). 512 blocks x 256.
// ---------------------------------------------------------------------------
__global__ void cast_hidden_kernel(const float* __restrict__ hid, ushort_t* __restrict__ hbf,
                                   float* __restrict__ macc) {
    int r0 = blockIdx.x * 16;
    float s[8];
#pragma unroll
    for (int j = 0; j < 8; ++j) s[j] = 0.f;
    for (int r = 0; r < 16; ++r) {
        const float* rp = hid + (size_t)(r0 + r) * Hd;
        ushort_t*    wp = hbf + (size_t)(r0 + r) * Hd;
#pragma unroll
        for (int j = 0; j < 2; ++j) {
            int c = j * 1024 + threadIdx.x * 4;
            float4 v = *(const float4*)(rp + c);
            s[j*4+0] += v.x; s[j*4+1] += v.y; s[j*4+2] += v.z; s[j*4+3] += v.w;
            u16x4 o;
            o[0] = f2bf(v.x); o[1] = f2bf(v.y); o[2] = f2bf(v.z); o[3] = f2bf(v.w);
            *(u16x4*)(wp + c) = o;
        }
    }
#pragma unroll
    for (int j = 0; j < 2; ++j)
#pragma unroll
        for (int q = 0; q < 4; ++q)
            atomicAdd(macc + j * 1024 + threadIdx.x * 4 + q, s[j*4+q]);
}

// ---------------------------------------------------------------------------
// mean_q[c] = dot(mean_h, Wq[c,:])  (f32 exact path). One wave per output c.
// ---------------------------------------------------------------------------
__global__ void meanq_kernel(const float* __restrict__ macc, const float* __restrict__ Wq,
                             float* __restrict__ mq) {
    int wid = blockIdx.x * 4 + (threadIdx.x >> 6);
    int lane = threadIdx.x & 63;
    const float inv = 1.f / 8192.f;
    float s = 0.f;
    for (int k = lane; k < Hd; k += 64) s += macc[k] * inv * Wq[(size_t)wid * Hd + k];
#pragma unroll
    for (int m = 32; m; m >>= 1) s += __shfl_xor(s, m, 64);
    if (lane == 0) mq[wid] = s;
}

// ---------------------------------------------------------------------------
// per-belief radius + rough score (f32 exact). One wave per row.
// ---------------------------------------------------------------------------
__global__ void beliefs_kernel(const float* __restrict__ ab, const float* __restrict__ mq,
                               float* __restrict__ radii, float* __restrict__ rsc) {
    int n = blockIdx.x * 4 + (threadIdx.x >> 6);
    int lane = threadIdx.x & 63;
    float rqv[4];
#pragma unroll
    for (int j = 0; j < 4; ++j) {
        int d = lane + 64 * j;
        float s = 0.f;
#pragma unroll
        for (int hh = 0; hh < 8; ++hh) s += mq[hh * 256 + d];
        rqv[j] = s * 0.125f;
    }
    float v[4]; float r2 = 0.f;
#pragma unroll
    for (int j = 0; j < 4; ++j) { v[j] = ab[(size_t)n * Dd + lane + 64 * j]; r2 += v[j] * v[j]; }
#pragma unroll
    for (int m = 32; m; m >>= 1) r2 += __shfl_xor(r2, m, 64);
    float r = fmaxf(sqrtf(r2), 1e-8f);
    float dq = 0.f;
#pragma unroll
    for (int j = 0; j < 4; ++j) dq += (v[j] / r) * rqv[j];
#pragma unroll
    for (int m = 32; m; m >>= 1) dq += __shfl_xor(dq, m, 64);
    if (lane == 0) { radii[n] = r; rsc[n] = dq; }
}

// ---------------------------------------------------------------------------
// single-block: top-64 (desc, ties -> lower index), gather keys/values,
// goal angles, goal bias, head scales.
// ---------------------------------------------------------------------------
__global__ void topk_kernel(const float* __restrict__ ab, const float* __restrict__ radii,
                            const float* __restrict__ rsc, const float* __restrict__ gemb,
                            const float* __restrict__ gprio, const float* __restrict__ Wgoal,
                            const float* __restrict__ ltemp,
                            ushort_t* __restrict__ keysg, ushort_t* __restrict__ valtg,
                            float* __restrict__ gbias, float* __restrict__ hscale) {
    __shared__ float s_sc[4096];
    __shared__ float s_rv[4];
    __shared__ int   s_ri[4];
    __shared__ int   s_top[64];
    __shared__ float s_ga[16 * 256];
    __shared__ float s_mga[256];
    __shared__ float s_gw[8];
    __shared__ float s_keyf[64 * 256];
    __shared__ float s_red[256];

    int t = threadIdx.x;
    int lane = t & 63, w = t >> 6;
    for (int it = 0; it < 16; ++it) s_sc[t + it * 256] = rsc[t + it * 256];
    __syncthreads();

    for (int kk = 0; kk < 64; ++kk) {
        float bv = -3.4e38f; int bi = 0x7fffffff;
#pragma unroll
        for (int j4 = 0; j4 < 4; ++j4) {
            f32x4 v4 = *(const f32x4*)&s_sc[t * 16 + j4 * 4];
#pragma unroll
            for (int q = 0; q < 4; ++q) {
                int idx = t * 16 + j4 * 4 + q;
                float v = v4[q];
                if (v > bv || (v == bv && idx < bi)) { bv = v; bi = idx; }
            }
        }
#pragma unroll
        for (int m = 32; m; m >>= 1) {
            float ov = __shfl_xor(bv, m, 64);
            int   oi = __shfl_xor(bi, m, 64);
            if (ov > bv || (ov == bv && oi < bi)) { bv = ov; bi = oi; }
        }
        if (lane == 0) { s_rv[w] = bv; s_ri[w] = bi; }
        __syncthreads();
        if (t == 0) {
            float fv = s_rv[0]; int fi = s_ri[0];
#pragma unroll
            for (int wv = 1; wv < 4; ++wv)
                if (s_rv[wv] > fv || (s_rv[wv] == fv && s_ri[wv] < fi)) { fv = s_rv[wv]; fi = s_ri[wv]; }
            s_top[kk] = fi; s_sc[fi] = -3.4e38f;
        }
        __syncthreads();
    }

    {
        int kk = t >> 2, dp = t & 3;
        int idx = s_top[kk];
        float r = radii[idx];
        const float4* src = (const float4*)(ab + (size_t)idx * Dd + dp * 64);
#pragma unroll 4
        for (int dd = 0; dd < 16; ++dd) {
            float4 v = src[dd];
            int d = dp * 64 + dd * 4;
            float k0 = v.x / r, k1 = v.y / r, k2 = v.z / r, k3 = v.w / r;
            s_keyf[kk * 256 + d + 0] = k0;
            s_keyf[kk * 256 + d + 1] = k1;
            s_keyf[kk * 256 + d + 2] = k2;
            s_keyf[kk * 256 + d + 3] = k3;
            u16x4 o;
            o[0] = f2bf(k0); o[1] = f2bf(k1); o[2] = f2bf(k2); o[3] = f2bf(k3);
            *(u16x4*)(keysg + kk * 256 + d) = o;
            valtg[(d + 0) * 64 + kk] = f2bf(v.x);
            valtg[(d + 1) * 64 + kk] = f2bf(v.y);
            valtg[(d + 2) * 64 + kk] = f2bf(v.z);
            valtg[(d + 3) * 64 + kk] = f2bf(v.w);
        }
    }
    {
        for (int g = w; g < 16; g += 4) {
            float v[4]; float r2 = 0.f;
#pragma unroll
            for (int j = 0; j < 4; ++j) { v[j] = gemb[g * 256 + lane + 64 * j]; r2 += v[j] * v[j]; }
#pragma unroll
            for (int m = 32; m; m >>= 1) r2 += __shfl_xor(r2, m, 64);
            float r = fmaxf(sqrtf(r2), 1e-8f);
#pragma unroll
            for (int j = 0; j < 4; ++j) s_ga[g * 256 + lane + 64 * j] = v[j] / r;
        }
    }
    __syncthreads();
    {
        float s = 0.f;
        for (int g = 0; g < 16; ++g) s += s_ga[g * 256 + t];
        s_mga[t] = s * (1.f / 16.f);
    }
    __syncthreads();
    if (t < 8) {
        float s = 0.f;
        for (int d = 0; d < 256; ++d) s += Wgoal[t * 256 + d] * s_mga[d];
        s_gw[t] = 1.f / (1.f + expf(-s));
        hscale[t] = fmaxf(expf(ltemp[t] + 0.1f), 0.1f) * (1.f / 16.f);
    }
    __syncthreads();
    {
        int kk = t & 63, gq = t >> 6;
        const f32x4* kp = (const f32x4*)&s_keyf[kk * 256];
        float best = -3.4e38f;
        for (int g = gq * 4; g < gq * 4 + 4; ++g) {
            const f32x4* gp_ = (const f32x4*)&s_ga[g * 256];
            float dot = 0.f;
            for (int d4 = 0; d4 < 64; ++d4) {
                f32x4 a = kp[d4], b = gp_[d4];
                dot += a[0] * b[0] + a[1] * b[1] + a[2] * b[2] + a[3] * b[3];
            }
            best = fmaxf(best, dot * gprio[g]);
        }
        s_red[t] = best;
    }
    __syncthreads();
    if (t < 64) {
        float m = fmaxf(fmaxf(s_red[t], s_red[t + 64]), fmaxf(s_red[t + 128], s_red[t + 192]));
        for (int hh = 0; hh < 8; ++hh) gbias[hh * 64 + t] = s_gw[hh] * m;
    }
}

// ---------------------------------------------------------------------------
// bf16 GEMM C = A[M,K] @ B[N,K]^T. 256x128 tile, BK=32, 4 waves (256 thr),
// wave tile 128x64 (2M x 2N), triple-buffered LDS (72KB -> 2 blocks/CU),
// counted vmcnt(6) pipeline, raw s_barrier (1/K-tile), both-sides XOR swizzle.
// EPI 2: [output|utility], gate inline from gpart+bg2.
// EPI 3: queries (bn<2048, bf16) + gate-GEMM (bn>=2048 -> atomicAdd gpart).
// ---------------------------------------------------------------------------
template <int EPI>
__global__ __launch_bounds__(256, 2)
void gemm_bt_kernel(const ushort_t* __restrict__ A, const ushort_t* __restrict__ Bw,
                    const ushort_t* __restrict__ Bw2, int Kd,
                    ushort_t* __restrict__ obf, float* __restrict__ of1, float* __restrict__ of2,
                    const float* __restrict__ bg1, const float* __restrict__ Wg2,
                    float* __restrict__ gpart, const float* __restrict__ bg2) {
    // [slot 0..2][A: 8192 ushort | B: 4096 ushort] = 72 KB
    __shared__ __align__(16) ushort_t lds[3 * 12288];

    const int tid  = threadIdx.x;
    const int lane = tid & 63;
    const int w    = tid >> 6;
    const int wr   = (w >> 1) * 128;     // 2 wave-rows (M)
    const int wc   = (w & 1) * 64;       // 2 wave-cols (N)

    // XCD swizzle (nwg % 8 == 0)
    const int nwg = gridDim.x * gridDim.y;
    const int lin = blockIdx.y * gridDim.x + blockIdx.x;
    const int swz = (lin & 7) * (nwg >> 3) + (lin >> 3);
    const int bm = (swz / gridDim.x) * 256, bn = (swz % gridDim.x) * 128;

    const ushort_t* Ab = A + (size_t)bm * Kd;
    const ushort_t* Bb;
    if (EPI == 3 && bn >= 2048) Bb = Bw2 + (size_t)(bn - 2048) * Kd;
    else                        Bb = Bw + (size_t)bn * Kd;

    // staging: A = 1024 chunks (4/thread), B = 512 chunks (2/thread).
    // chunk c -> row = c>>2, phys cb = c&3; fetch logical
    // cbl = cb ^ (row&3) ^ ((row>>2)&3) so LDS holds the swizzled layout.
    int cA[4], cB[2]; size_t sA[4], sB[2];
#pragma unroll
    for (int j = 0; j < 4; ++j) {
        int c = tid + j * 256, r = c >> 2;
        int cbl = (c & 3) ^ (r & 3) ^ ((r >> 2) & 3);
        cA[j] = c; sA[j] = (size_t)r * Kd + cbl * 8;
    }
#pragma unroll
    for (int j = 0; j < 2; ++j) {
        int c = tid + j * 256, r = c >> 2;
        int cbl = (c & 3) ^ (r & 3) ^ ((r >> 2) & 3);
        cB[j] = c; sB[j] = (size_t)r * Kd + cbl * 8;
    }

    // reader: physical chunk per lane (mi/ni-independent)
    const int pcb = (lane >> 4) ^ (lane & 3) ^ ((lane >> 2) & 3);
    const int aBase = (wr + (lane & 15)) * 32 + pcb * 8;
    const int bBase = 8192 + (wc + (lane & 15)) * 32 + pcb * 8;

    f32x4 acc[8][4];
#pragma unroll
    for (int mi = 0; mi < 8; ++mi)
#pragma unroll
        for (int ni = 0; ni < 4; ++ni)
#pragma unroll
            for (int q = 0; q < 4; ++q) acc[mi][ni][q] = 0.f;

    const int NT = Kd >> 5;   // K-tiles of 32

#define STAGE_T(t_, slot_) do {                                            \
        const ushort_t* As_ = Ab + (size_t)(t_) * 32;                      \
        const ushort_t* Bs_ = Bb + (size_t)(t_) * 32;                      \
        ushort_t* ls_ = lds + (slot_) * 12288;                             \
        GLL16(As_ + sA[0], ls_ + cA[0] * 8);                               \
        GLL16(As_ + sA[1], ls_ + cA[1] * 8);                               \
        GLL16(As_ + sA[2], ls_ + cA[2] * 8);                               \
        GLL16(As_ + sA[3], ls_ + cA[3] * 8);                               \
        GLL16(Bs_ + sB[0], ls_ + 8192 + cB[0] * 8);                        \
        GLL16(Bs_ + sB[1], ls_ + 8192 + cB[1] * 8);                        \
    } while (0)

    // prologue: stage tiles 0 and 1
    STAGE_T(0, 0);
    STAGE_T(1, 1);

    int slot = 0;
    for (int t = 0; t < NT; ++t) {
        if (t >= NT - 2) asm volatile("s_waitcnt vmcnt(0)" ::: "memory");
        else             asm volatile("s_waitcnt vmcnt(6)" ::: "memory");
        __builtin_amdgcn_s_barrier();
        __builtin_amdgcn_sched_barrier(0);

        const ushort_t* sl = lds + slot * 12288;
        bf16x8 afr[8], bfr[4];
#pragma unroll
        for (int mi = 0; mi < 8; ++mi)
            afr[mi] = *(const bf16x8*)(sl + aBase + mi * 512);
#pragma unroll
        for (int ni = 0; ni < 4; ++ni)
            bfr[ni] = *(const bf16x8*)(sl + bBase + ni * 512);

        if (t + 2 < NT) {
            int s2 = slot + 2; if (s2 >= 3) s2 -= 3;
            STAGE_T(t + 2, s2);
        }

        __builtin_amdgcn_s_setprio(1);
#pragma unroll
        for (int mi = 0; mi < 8; ++mi)
#pragma unroll
            for (int ni = 0; ni < 4; ++ni)
                acc[mi][ni] = __builtin_amdgcn_mfma_f32_16x16x32_bf16(afr[mi], bfr[ni], acc[mi][ni], 0, 0, 0);
        __builtin_amdgcn_s_setprio(0);

        ++slot; if (slot >= 3) slot = 0;
    }
#undef STAGE_T

    if (EPI == 2) {
        const float b2 = bg2[0];
#pragma unroll
        for (int mi = 0; mi < 8; ++mi)
#pragma unroll
            for (int r = 0; r < 4; ++r) {
                int row = bm + wr + mi * 16 + (lane >> 4) * 4 + r;
                float g = gpart[row] + b2;
                float sg = (g > 0.f) ? 1.f : ((g < 0.f) ? -1.f : 0.f);
                float ss = sg * sqrtf(fmaxf(fabsf(g), 1e-6f));
                float gv = 1.f / (1.f + expf(-ss));
#pragma unroll
                for (int ni = 0; ni < 4; ++ni) {
                    int col = bn + wc + ni * 16 + (lane & 15);
                    float v = acc[mi][ni][r];
                    if (col < 2048) of1[(size_t)row * 2048 + col] = gv * v;
                    else            of2[(size_t)row * 2048 + (col - 2048)] = v;
                }
            }
    } else {  // EPI == 3
        if (bn < 2048) {
#pragma unroll
            for (int mi = 0; mi < 8; ++mi)
#pragma unroll
                for (int ni = 0; ni < 4; ++ni)
#pragma unroll
                    for (int r = 0; r < 4; ++r) {
                        int row = bm + wr + mi * 16 + (lane >> 4) * 4 + r;
                        int col = bn + wc + ni * 16 + (lane & 15);
                        obf[(size_t)row * 2048 + col] = f2bf(acc[mi][ni][r]);
                    }
        } else {
            float wg[4], bb[4];
#pragma unroll
            for (int ni = 0; ni < 4; ++ni) {
                int col = bn + wc + ni * 16 + (lane & 15) - 2048;
                wg[ni] = Wg2[col]; bb[ni] = bg1[col];
            }
#pragma unroll
            for (int mi = 0; mi < 8; ++mi)
#pragma unroll
                for (int r = 0; r < 4; ++r) {
                    float s = 0.f;
#pragma unroll
                    for (int ni = 0; ni < 4; ++ni) {
                        float v = acc[mi][ni][r] + bb[ni];
                        v = fmaxf(v, 0.f);
                        s += v * wg[ni];
                    }
#pragma unroll
                    for (int m = 8; m; m >>= 1) s += __shfl_xor(s, m, 64);
                    if ((lane & 15) == 0)
                        atomicAdd(gpart + bm + wr + mi * 16 + (lane >> 4) * 4 + r, s);
                }
        }
    }
}

// ---------------------------------------------------------------------------
// attention: 32 rows/block, 4 waves, 1 head/wave; grid (256, 2).
// Q direct global->reg; LDS 80KB -> 2 blocks/CU.
// ---------------------------------------------------------------------------
__global__ __launch_bounds__(256, 2)
void attn_kernel(const ushort_t* __restrict__ qry, const ushort_t* __restrict__ keysg,
                 const ushort_t* __restrict__ valtg, const float* __restrict__ gbias,
                 const float* __restrict__ hscale, float* __restrict__ attn_out,
                 float* __restrict__ retr_out, ushort_t* __restrict__ flatb) {
    __shared__ ushort_t sK[64 * 256];
    __shared__ ushort_t sV[256 * 64];
    __shared__ ushort_t sP[4][32 * 64];

    const int tid = threadIdx.x, lane = tid & 63, w = tid >> 6;
    const int r0 = blockIdx.x * 32;
    const int head = blockIdx.y * 4 + w;

    for (int it = 0; it < 8; ++it) {
        int f = it * 256 + tid;
        int row = f >> 5, cb = f & 31;
        u16x8 v = *(const u16x8*)(keysg + f * 8);
        int byte = (row * 512 + cb * 16) ^ ((row & 7) << 4);
        *(u16x8*)((char*)sK + byte) = v;
    }
    for (int it = 0; it < 8; ++it) {
        int f = it * 256 + tid;
        int row = f >> 3, cb = f & 7;
        u16x8 v = *(const u16x8*)(valtg + f * 8);
        int byte = (row * 128 + cb * 16) ^ ((row & 7) << 4);
        *(u16x8*)((char*)sV + byte) = v;
    }
    __syncthreads();

    char* sPw = (char*)sP[w];
    const float hs = hscale[head];
    float gb[4];
#pragma unroll
    for (int ni = 0; ni < 4; ++ni) gb[ni] = gbias[head * 64 + ni * 16 + (lane & 15)];

    const ushort_t* qbase = qry + (size_t)r0 * Cd + head * 256
                          + (size_t)(lane & 15) * Cd + (lane >> 4) * 8;

    f32x4 accs[2][4];
#pragma unroll
    for (int mi = 0; mi < 2; ++mi)
#pragma unroll
        for (int ni = 0; ni < 4; ++ni)
#pragma unroll
            for (int q = 0; q < 4; ++q) accs[mi][ni][q] = 0.f;

#pragma unroll
    for (int kt = 0; kt < 8; ++kt) {
        const int kb = kt * 64 + (lane >> 4) * 16;
        bf16x8 aq[2], bk[4];
#pragma unroll
        for (int mi = 0; mi < 2; ++mi)
            aq[mi] = *(const bf16x8*)(qbase + (size_t)(mi * 16) * Cd + kt * 32);
#pragma unroll
        for (int ni = 0; ni < 4; ++ni) {
            int n = ni * 16 + (lane & 15);
            bk[ni] = *(const bf16x8*)((const char*)sK + ((n * 512 + kb) ^ ((n & 7) << 4)));
        }
#pragma unroll
        for (int mi = 0; mi < 2; ++mi)
#pragma unroll
            for (int ni = 0; ni < 4; ++ni)
                accs[mi][ni] = __builtin_amdgcn_mfma_f32_16x16x32_bf16(aq[mi], bk[ni], accs[mi][ni], 0, 0, 0);
    }

#pragma unroll
    for (int mi = 0; mi < 2; ++mi)
#pragma unroll
        for (int r = 0; r < 4; ++r) {
            float sc[4];
            float mx = -3.4e38f;
#pragma unroll
            for (int ni = 0; ni < 4; ++ni) {
                sc[ni] = accs[mi][ni][r] * hs + gb[ni];
                mx = fmaxf(mx, sc[ni]);
            }
#pragma unroll
            for (int m = 8; m; m >>= 1) mx = fmaxf(mx, __shfl_xor(mx, m, 64));
            float p[4]; float sm = 0.f;
#pragma unroll
            for (int ni = 0; ni < 4; ++ni) { p[ni] = expf(sc[ni] - mx); sm += p[ni]; }
#pragma unroll
            for (int m = 8; m; m >>= 1) sm += __shfl_xor(sm, m, 64);
            float inv = 1.f / sm;
            int row = mi * 16 + (lane >> 4) * 4 + r;
            size_t ob = (size_t)(r0 + row) * 512 + head * 64;
#pragma unroll
            for (int ni = 0; ni < 4; ++ni) {
                float a = p[ni] * inv;
                int col = ni * 16 + (lane & 15);
                attn_out[ob + col] = a;
                int byte = (row * 128 + col * 2) ^ ((row & 7) << 4);
                *(ushort_t*)(sPw + byte) = f2bf(a);
            }
        }

    f32x4 accr[2][16];
#pragma unroll
    for (int mi = 0; mi < 2; ++mi)
#pragma unroll
        for (int ni = 0; ni < 16; ++ni)
#pragma unroll
            for (int q = 0; q < 4; ++q) accr[mi][ni][q] = 0.f;

#pragma unroll
    for (int kt = 0; kt < 2; ++kt) {
        const int kb = kt * 64 + (lane >> 4) * 16;
        bf16x8 ap[2];
#pragma unroll
        for (int mi = 0; mi < 2; ++mi) {
            int m = mi * 16 + (lane & 15);
            ap[mi] = *(const bf16x8*)(sPw + ((m * 128 + kb) ^ ((m & 7) << 4)));
        }
#pragma unroll
        for (int ni = 0; ni < 16; ++ni) {
            int n = ni * 16 + (lane & 15);
            bf16x8 bv = *(const bf16x8*)((const char*)sV + ((n * 128 + kb) ^ ((n & 7) << 4)));
            accr[0][ni] = __builtin_amdgcn_mfma_f32_16x16x32_bf16(ap[0], bv, accr[0][ni], 0, 0, 0);
            accr[1][ni] = __builtin_amdgcn_mfma_f32_16x16x32_bf16(ap[1], bv, accr[1][ni], 0, 0, 0);
        }
    }

#pragma unroll
    for (int mi = 0; mi < 2; ++mi)
#pragma unroll
        for (int ni = 0; ni < 16; ++ni)
#pragma unroll
            for (int r = 0; r < 4; ++r) {
                int row = mi * 16 + (lane >> 4) * 4 + r;
                int d = ni * 16 + (lane & 15);
                float v = accr[mi][ni][r];
                size_t o = (size_t)(r0 + row) * Cd + head * 256 + d;
                retr_out[o] = v;
                flatb[o] = f2bf(v);
            }
}

// ---------------------------------------------------------------------------
// depthwise causal conv (k=4) + SiLU residual, 4 channels/thread.
// ---------------------------------------------------------------------------
__global__ void conv_kernel(const ushort_t* __restrict__ flat, const float* __restrict__ cw,
                            ushort_t* __restrict__ flat2) {
    int cq = blockIdx.x * 256 + threadIdx.x;
    int c  = cq * 4;
    int b  = blockIdx.z;
    int t0 = blockIdx.y * 32;
    float4 wv[4];
#pragma unroll
    for (int j = 0; j < 4; ++j) wv[j] = *(const float4*)(cw + (size_t)(c + j) * 4);
    size_t base = (size_t)b * 2048 * Cd + c;
    float xm3[4], xm2[4], xm1[4];
    if (t0 == 0) {
#pragma unroll
        for (int j = 0; j < 4; ++j) { xm3[j] = 0.f; xm2[j] = 0.f; xm1[j] = 0.f; }
    } else {
        u16x4 a3 = *(const u16x4*)(flat + base + (size_t)(t0 - 3) * Cd);
        u16x4 a2 = *(const u16x4*)(flat + base + (size_t)(t0 - 2) * Cd);
        u16x4 a1 = *(const u16x4*)(flat + base + (size_t)(t0 - 1) * Cd);
#pragma unroll
        for (int j = 0; j < 4; ++j) { xm3[j] = bf2f(a3[j]); xm2[j] = bf2f(a2[j]); xm1[j] = bf2f(a1[j]); }
    }
    for (int t = t0; t < t0 + 32; ++t) {
        u16x4 xv = *(const u16x4*)(flat + base + (size_t)t * Cd);
        u16x4 ov;
#pragma unroll
        for (int j = 0; j < 4; ++j) {
            float x = bf2f(xv[j]);
            float cv = wv[j].x * xm3[j] + wv[j].y * xm2[j] + wv[j].z * xm1[j] + wv[j].w * x;
            float sl = cv / (1.f + expf(-cv));
            ov[j] = f2bf(x + sl);
            xm3[j] = xm2[j]; xm2[j] = xm1[j]; xm1[j] = x;
        }
        *(u16x4*)(flat2 + base + (size_t)t * Cd) = ov;
    }
}

// ---------------------------------------------------------------------------
extern "C" void kernel_launch(void* const* d_in, const int* in_sizes, int n_in,
                              void* d_out, int out_size, void* d_ws, size_t ws_size,
                              hipStream_t stream) {
    (void)in_sizes; (void)n_in; (void)out_size; (void)ws_size;
    const float* hid   = (const float*)d_in[0];
    const float* ab    = (const float*)d_in[1];
    const float* gemb  = (const float*)d_in[2];
    const float* gprio = (const float*)d_in[3];
    const float* Wq    = (const float*)d_in[4];
    const float* Wo    = (const float*)d_in[5];
    const float* Wgoal = (const float*)d_in[6];
    const float* ltemp = (const float*)d_in[7];
    const float* Wu    = (const float*)d_in[8];
    const float* Wg1   = (const float*)d_in[9];
    const float* bg1   = (const float*)d_in[10];
    const float* Wg2   = (const float*)d_in[11];
    const float* bg2   = (const float*)d_in[12];
    const float* cw    = (const float*)d_in[13];

    float* out      = (float*)d_out;
    float* out_util = out + 16777216;
    float* out_attn = out + 33554432;
    float* out_retr = out + 37748736;

    char* ws = (char*)d_ws;
    ushort_t* hbf    = (ushort_t*)(ws + O_HID);
    ushort_t* wqb    = (ushort_t*)(ws + O_WQ);
    ushort_t* wowub  = (ushort_t*)(ws + O_WOWU);
    ushort_t* wg1b   = (ushort_t*)(ws + O_WG1);
    ushort_t* qryb   = (ushort_t*)(ws + O_QRY);
    ushort_t* flatb  = hbf;                       // alias: attn after GEMM on hidden
    float* macc   = (float*)(ws + O_MEANACC);
    float* meanq  = (float*)(ws + O_MEANQ);
    float* radii  = (float*)(ws + O_RAD);
    float* rsc    = (float*)(ws + O_RSC);
    ushort_t* keysb = (ushort_t*)(ws + O_KEYS);
    ushort_t* valtb = (ushort_t*)(ws + O_VALT);
    float* gbias  = (float*)(ws + O_GB);
    float* hscale = (float*)(ws + O_HS);
    float* gpart  = (float*)(ws + O_GP);

    hipMemsetAsync(ws + O_MEANACC, 0, MEMSET_SZ, stream);

    cast_hidden_kernel<<<512, 256, 0, stream>>>(hid, hbf, macc);
    cast4_kernel<<<2048, 256, 0, stream>>>(Wq, wqb, 2048 * 2048,
                                           Wo, wowub, 2048 * 2048,
                                           Wu, wowub + 2048 * 2048, 2048 * 2048,
                                           Wg1, wg1b, 512 * 2048);

    meanq_kernel<<<512, 256, 0, stream>>>(macc, Wq, meanq);
    beliefs_kernel<<<1024, 256, 0, stream>>>(ab, meanq, radii, rsc);
    topk_kernel<<<1, 256, 0, stream>>>(ab, radii, rsc, gemb, gprio, Wgoal, ltemp,
                                       keysb, valtb, gbias, hscale);

    // fused queries + gate partials: 256x128 tiles; cols 0..2047 queries,
    // 2048..2559 gate (4 tiles). grid 20x32 = 640 blocks @ 2/CU.
    gemm_bt_kernel<3><<<dim3(20, 32), 256, 0, stream>>>(hbf, wqb, wg1b, 2048,
        qryb, nullptr, nullptr, bg1, Wg2, gpart, nullptr);

    attn_kernel<<<dim3(256, 2), 256, 0, stream>>>(qryb, keysb, valtb, gbias, hscale,
                                                  out_attn, out_retr, flatb);

    conv_kernel<<<dim3(2, 64, 4), 256, 0, stream>>>(flatb, cw, qryb /* flat2 */);

    // [output | utility] = flat2 @ [Wo;Wu]^T; gate from gpart+bg2 inline.
    // grid 32x32 = 1024 blocks @ 2/CU (2 exact rounds).
    gemm_bt_kernel<2><<<dim3(32, 32), 256, 0, stream>>>(qryb, wowub, nullptr, 2048,
        nullptr, out, out_util, nullptr, nullptr, gpart, bg2);
}